// Round 12
// baseline (825.654 us; speedup 1.0000x reference)
//
#include <hip/hip_runtime.h>
#include <stdint.h>

typedef float f32x4 __attribute__((ext_vector_type(4)));
typedef __bf16 bf16x8 __attribute__((ext_vector_type(8)));
typedef unsigned short u16;
typedef unsigned short u16x8 __attribute__((ext_vector_type(8)));

__device__ __forceinline__ float bf2f(u16 u){ unsigned int i = ((unsigned int)u)<<16; float f; __builtin_memcpy(&f,&i,4); return f; }
__device__ __forceinline__ u16 f2bf(float f){ unsigned int i; __builtin_memcpy(&i,&f,4); i += 0x7FFFu + ((i>>16)&1u); return (u16)(i>>16); }
__device__ __forceinline__ u16 f2h(float f){ _Float16 h = (_Float16)f; u16 b; __builtin_memcpy(&b,&h,2); return b; }
__device__ __forceinline__ float h2f(u16 b){ _Float16 h; __builtin_memcpy(&h,&b,2); return (float)h; }

__device__ __forceinline__ void gld16(const void* g, void* l){
  __builtin_amdgcn_global_load_lds(
      (const __attribute__((address_space(1))) void*)(uintptr_t)g,
      (__attribute__((address_space(3))) void*)(unsigned int)(uintptr_t)l, 16, 0, 0);
}

// ---------------------------------------------------------------------------
// Zero only the border of Xpad [4][66][66][1024] (interior is fully
// overwritten by pad_interior each call; S3 aliasing clobbers borders
// between calls, so borders must be re-zeroed per call).
__global__ __launch_bounds__(256) void border_zero(u16* __restrict__ Xpad){
  const int n = blockIdx.y, p = blockIdx.x;   // p in 0..259
  int y, x;
  if (p < 66)        { y = 0;        x = p; }
  else if (p < 132)  { y = 65;       x = p - 66; }
  else if (p < 196)  { y = p - 131;  x = 0; }     // y = 1..64
  else               { y = p - 195;  x = 65; }    // y = 1..64
  u16x8 z = {};
  *(u16x8*)(Xpad + (((long)n*66 + y)*66 + x)*1024 + threadIdx.x*8)        = z;
  *(u16x8*)(Xpad + (((long)n*66 + y)*66 + x)*1024 + 2048 + threadIdx.x*8) = z;
}

// Prep: concat(T1,T2) NCHW f32 -> Xpad interior bf16.
__global__ __launch_bounds__(256) void pad_interior(const float* __restrict__ T1,
                                                    const float* __restrict__ T2,
                                                    u16* __restrict__ Xpad){
  const int n = blockIdx.z, ct = blockIdx.y, pt = blockIdx.x;
  const int t = threadIdx.x;
  const int c0 = ct*64, p0 = pt*64;
  const float* src = (c0 < 512) ? (T1 + ((long)n*512 + c0)*4096)
                                : (T2 + ((long)n*512 + (c0-512))*4096);
  __shared__ u16 lds[64][66];
  #pragma unroll
  for (int i=0;i<4;i++){
    int c = i*16 + (t>>4);
    int ch = t&15;
    float4 v = *(const float4*)(src + (long)c*4096 + p0 + ch*4);
    int p = ch*4;
    lds[p+0][c] = f2bf(v.x); lds[p+1][c] = f2bf(v.y);
    lds[p+2][c] = f2bf(v.z); lds[p+3][c] = f2bf(v.w);
  }
  __syncthreads();
  #pragma unroll
  for (int i=0;i<8;i++){
    int p = i*8 + (t>>5);
    int c2 = t&31;
    int pix = p0 + p; int yy = (pix>>6)+1, xx = (pix&63)+1;
    ushort2 val; val.x = lds[p][2*c2]; val.y = lds[p][2*c2+1];
    *(ushort2*)(Xpad + (((long)n*66 + yy)*66 + xx)*1024 + c0 + 2*c2) = val;
  }
}

// w_conv3 [o][ci][3][3] f32 -> wk3t [o][tap][ci] bf16
__global__ __launch_bounds__(256) void prep_w3(const float* __restrict__ w3, u16* __restrict__ wk3t){
  const int o = blockIdx.x; const int t = threadIdx.x;
  __shared__ u16 lds[9216];
  const float* src = w3 + (long)o*9216;
  #pragma unroll
  for (int i=0;i<9;i++){
    int j = i*256 + t;
    float4 v = *(const float4*)(src + j*4);
    lds[j*4+0]=f2bf(v.x); lds[j*4+1]=f2bf(v.y); lds[j*4+2]=f2bf(v.z); lds[j*4+3]=f2bf(v.w);
  }
  __syncthreads();
  u16* dst = wk3t + (long)o*9216;
  #pragma unroll
  for (int i=0;i<36;i++){
    int j = i*256 + t; int tp = j>>10, ci = j&1023;
    dst[j] = lds[ci*9+tp];
  }
}

// merged small prep: w1t (2048 blocks), lint (1024 blocks), bias1 (2 blocks)
__global__ void prep_small(const float* __restrict__ w1, const float* __restrict__ bg,
                           const float* __restrict__ bb, const float* __restrict__ bm,
                           const float* __restrict__ bv, const float* __restrict__ linw,
                           u16* __restrict__ w1t, u16* __restrict__ lint,
                           float* __restrict__ bias1){
  const int b = blockIdx.x, t = threadIdx.x;
  if (b < 2048){
    long i = (long)b*256 + t;
    int o = (int)(i>>10);
    float inv = bg[o] / sqrtf(bv[o] + 1e-5f);
    w1t[i] = f2bf(w1[i]*inv);
  } else if (b < 3072){
    long i = (long)(b-2048)*256 + t;
    lint[i] = f2bf(linw[i]);
  } else {
    int o = (b-3072)*256 + t;
    float inv = bg[o]/sqrtf(bv[o]+1e-5f);
    bias1[o] = bb[o] - bm[o]*inv;
  }
}

// per-row squared norm of bf16 [rows][512] -> f32 (softmax shift reference)
__global__ __launch_bounds__(256) void row_norm(const u16* __restrict__ x, float* __restrict__ nrm){
  const int row = blockIdx.x*4 + (threadIdx.x>>6);
  const int lane = threadIdx.x & 63;
  u16x8 q = *(const u16x8*)(x + (long)row*512 + lane*8);
  float s = 0.f;
  #pragma unroll
  for (int j=0;j<8;j++){ float f = bf2f(q[j]); s += f*f; }
  #pragma unroll
  for (int off=32; off; off>>=1) s += __shfl_xor(s, off);
  if (lane==0) nrm[row] = s;
}

// bf16 transpose: dst[c][r] = src[r][c], tiles 64x64
__global__ __launch_bounds__(256) void transpose_bf(const u16* __restrict__ src, u16* __restrict__ dst,
                                                    int R, int C, long sStr, long dStr){
  const int z = blockIdx.z;
  src += (long)z*sStr; dst += (long)z*dStr;
  const int r0 = blockIdx.x*64, c0 = blockIdx.y*64;
  const int t = threadIdx.x;
  __shared__ u16 lds[64][66];
  #pragma unroll
  for (int i=0;i<4;i++){
    int r = i*16 + (t>>4), ch = t&15;
    ushort4 v = *(const ushort4*)(src + (long)(r0+r)*C + c0 + ch*4);
    lds[r][ch*4+0]=v.x; lds[r][ch*4+1]=v.y; lds[r][ch*4+2]=v.z; lds[r][ch*4+3]=v.w;
  }
  __syncthreads();
  #pragma unroll
  for (int i=0;i<4;i++){
    int c = i*16 + (t>>4), ch = t&15;
    ushort4 v;
    v.x = lds[ch*4+0][c]; v.y = lds[ch*4+1][c]; v.z = lds[ch*4+2][c]; v.w = lds[ch*4+3][c];
    *(ushort4*)(dst + (long)(c0+c)*R + r0 + ch*4) = v;
  }
}

// bf16 [4096][512] -> f32 NCHW [512][4096] transpose (final output)
__global__ __launch_bounds__(256) void transpose_bf_f32(const u16* __restrict__ src, float* __restrict__ dst){
  const int z = blockIdx.z;
  src += (long)z*4096*512; dst += (long)z*512*4096;
  const int r0 = blockIdx.x*64, c0 = blockIdx.y*64;
  const int t = threadIdx.x;
  __shared__ u16 lds[64][66];
  #pragma unroll
  for (int i=0;i<4;i++){
    int r = i*16 + (t>>4), ch = t&15;
    ushort4 v = *(const ushort4*)(src + (long)(r0+r)*512 + c0 + ch*4);
    lds[r][ch*4+0]=v.x; lds[r][ch*4+1]=v.y; lds[r][ch*4+2]=v.z; lds[r][ch*4+3]=v.w;
  }
  __syncthreads();
  #pragma unroll
  for (int i=0;i<4;i++){
    int c = i*16 + (t>>4), ch = t&15;
    float4 v;
    v.x = bf2f(lds[ch*4+0][c]); v.y = bf2f(lds[ch*4+1][c]);
    v.z = bf2f(lds[ch*4+2][c]); v.w = bf2f(lds[ch*4+3][c]);
    *(float4*)(dst + (long)(c0+c)*4096 + r0 + ch*4) = v;
  }
}

// ---------------------------------------------------------------------------
// 256x256 bf16 MFMA GEMM, BK=64, 8 waves. Single-wait deep pipeline: all 4
// sub-stages of tile t+1 issued up-front, ONE vmcnt(8) per tile (oldest 8 =
// all of tile t resident, 8 in flight), one barrier, 64-MFMA block, barrier.
// EPI 0: bf16 store (conv3). EPI 3: SYMMETRIC batched S = x.x^T (544 blocks,
// upper-tri; off-diag writes transposed tile via LDS reuse, bit-identical).
template<int EPI, int CONV>
__global__ __launch_bounds__(512, 2) void gemm256(
    const u16* __restrict__ Ain, const u16* __restrict__ Btin, void* __restrict__ Cv,
    int K, int lda, int ldb, int ldc, const float* __restrict__ srowIn,
    u16* __restrict__ C0, u16* __restrict__ C1, u16* __restrict__ C2, u16* __restrict__ C3)
{
  extern __shared__ u16 sm[];
  const int t = threadIdx.x;
  const int lane = t & 63;
  const int wid = t >> 6;
  const int wr = wid >> 2, wc = wid & 3;

  long m0, n0;
  int byv = 0, bxv = 0;
  const u16* A; const u16* Bt; const float* srow; u16* Cz;
  if (EPI == 3){
    const int orig = blockIdx.x;                 // 544 blocks
    const int swz = (orig & 7) * 68 + (orig >> 3);
    const int z = swz / 136;
    int p = swz % 136;
    int by = 0;
    while (p >= 16 - by){ p -= 16 - by; by++; }
    const int bx = by + p;                       // by <= bx
    byv = by; bxv = bx;
    m0 = (long)by * 256; n0 = (long)bx * 256;
    A = Ain + (long)z*4096*lda;
    Bt = A;
    srow = srowIn + (long)z*4096;
    Cz = (z==0)?C0:(z==1)?C1:(z==2)?C2:C3;
  } else {
    const int orig = blockIdx.y * gridDim.x + blockIdx.x;
    const int cpx = (gridDim.x * gridDim.y) >> 3;
    const int swz = (orig & 7) * cpx + (orig >> 3);
    const int bx = swz % gridDim.x;
    const int by = swz / gridDim.x;
    m0 = (long)by * 256; n0 = (long)bx * 256;
    A = Ain; Bt = Btin; srow = srowIn; Cz = (u16*)Cv;
  }

  const int row0 = t >> 2;
  const int cs0  = (t & 3) ^ ((row0 >> 1) & 3);

  const u16 *aB0, *aB1;
  if (CONV) {
    long m_ = m0 + row0;
    long pb0 = ((long)((int)(m_>>12)*66 + (int)((m_>>6)&63)))*66 + (int)(m_&63);
    m_ = m0 + row0 + 128;
    long pb1 = ((long)((int)(m_>>12)*66 + (int)((m_>>6)&63)))*66 + (int)(m_&63);
    aB0 = A + pb0*1024 + cs0*8;
    aB1 = A + pb1*1024 + cs0*8;
  } else {
    aB0 = A + (m0 + row0)*(long)lda + cs0*8;
    aB1 = A + (m0 + row0 + 128)*(long)lda + cs0*8;
  }
  const u16* bB0 = Bt + (n0 + row0)*(long)ldb + cs0*8;
  const u16* bB1 = Bt + (n0 + row0 + 128)*(long)ldb + cs0*8;

  auto issueA = [&](int sub, long aoff){
    u16* d = sm + sub*8192 + t*8;
    gld16(aB0 + aoff, d);
    gld16(aB1 + aoff, d + 4096);
  };
  auto issueB = [&](int sub, long boff){
    u16* d = sm + 32768 + sub*8192 + t*8;
    gld16(bB0 + boff, d);
    gld16(bB1 + boff, d + 4096);
  };
  auto conv_aoff = [&](int tile)->long {
    int kb = tile << 6;
    int tap = kb >> 10;
    int cb  = kb & 1023;
    int ky = (tap >= 6) ? 2 : (tap >= 3 ? 1 : 0);
    int kx = tap - ky*3;
    return (long)(ky*66 + kx)*1024 + cb;
  };

  const int frow = lane & 15;
  const int elemoff = (((lane>>4) ^ ((frow>>1)&3)) << 3);
  const int rAoff = (wr*128 + frow)*32 + elemoff;
  const int rBoff = (wc*64  + frow)*32 + elemoff;

  f32x4 acc[8][4] = {};

  // prologue: stage tile 0 fully (8 loads/thread, oldest group)
  {
    long a0 = CONV ? conv_aoff(0) : 0L;
    issueA(0, a0);       issueA(1, a0 + 32);
    issueB(0, 0);        issueB(1, 32);
  }

  const int NT = K >> 6;
  for (int tile = 0; tile < NT; ++tile) {
    const int b = tile & 1;
    const int nb2 = b ^ 1;
    const bool lastT = (tile == NT-1);

    // issue ALL of tile t+1 (8 loads/thread) before the single wait
    if (!lastT) {
      long aoffN = CONV ? conv_aoff(tile+1) : (long)(tile+1)*64;
      long boffN = (long)(tile+1)*64;
      issueA(nb2*2+0, aoffN);      issueA(nb2*2+1, aoffN + 32);
      issueB(nb2*2+0, boffN);      issueB(nb2*2+1, boffN + 32);
    }

    // single wait: oldest 8 (all of tile t) resident; 8 (tile t+1) in flight
    if (lastT) asm volatile("s_waitcnt vmcnt(0)" ::: "memory");
    else       asm volatile("s_waitcnt vmcnt(8)" ::: "memory");
    __builtin_amdgcn_s_barrier();
    __builtin_amdgcn_sched_barrier(0);

    // uninterrupted 64-MFMA compute over both K-halves of tile t
    #pragma unroll
    for (int half = 0; half < 2; ++half){
      const u16* pA = sm + (b*2+half)*8192 + rAoff;
      const u16* pB = sm + 32768 + (b*2+half)*8192 + rBoff;
      bf16x8 bf[4];
      #pragma unroll
      for (int i=0;i<4;i++) bf[i] = *(const bf16x8*)(pB + i*512);
      {
        bf16x8 a[4];
        #pragma unroll
        for (int i=0;i<4;i++) a[i] = *(const bf16x8*)(pA + i*512);
        __builtin_amdgcn_s_setprio(1);
        #pragma unroll
        for (int mi=0;mi<4;mi++)
          #pragma unroll
          for (int ni=0;ni<4;ni++)
            acc[mi][ni] = __builtin_amdgcn_mfma_f32_16x16x32_bf16(a[mi], bf[ni], acc[mi][ni],0,0,0);
        __builtin_amdgcn_s_setprio(0);
      }
      {
        bf16x8 a[4];
        #pragma unroll
        for (int i=0;i<4;i++) a[i] = *(const bf16x8*)(pA + (4+i)*512);
        __builtin_amdgcn_s_setprio(1);
        #pragma unroll
        for (int mi=0;mi<4;mi++)
          #pragma unroll
          for (int ni=0;ni<4;ni++)
            acc[4+mi][ni] = __builtin_amdgcn_mfma_f32_16x16x32_bf16(a[mi], bf[ni], acc[4+mi][ni],0,0,0);
        __builtin_amdgcn_s_setprio(0);
      }
    }

    // end barrier: all waves done reading buf b before tile t+1 writes it
    __builtin_amdgcn_s_barrier();
    __builtin_amdgcn_sched_barrier(0);
  }

  const int crow0 = wr*128 + ((lane>>4)<<2);
  const int ccol0 = wc*64 + frow;

  #pragma unroll
  for (int mi=0;mi<8;mi++){
    #pragma unroll
    for (int ni=0;ni<4;ni++){
      long col = n0 + ccol0 + ni*16;
      #pragma unroll
      for (int r=0;r<4;r++){
        long row = m0 + crow0 + mi*16 + r;
        float v = acc[mi][ni][r];
        if (EPI==3) Cz[row*(long)ldc + col] = f2h(v - srow[row]);
        else        Cz[row*(long)ldc + col] = f2bf(v);
      }
    }
  }

  if (EPI == 3 && bxv != byv){
    __syncthreads();
    u16* lt = sm;
    float sc[4];
    #pragma unroll
    for (int ni=0;ni<4;ni++) sc[ni] = srow[n0 + ccol0 + ni*16];
    #pragma unroll
    for (int mi=0;mi<8;mi++){
      const int g = (crow0 + mi*16) >> 2;
      #pragma unroll
      for (int ni=0;ni<4;ni++){
        const int col_l = ccol0 + ni*16;
        ushort4 pk;
        #pragma unroll
        for (int r=0;r<4;r++) pk[r] = f2h(acc[mi][ni][r] - sc[ni]);
        *(ushort4*)(lt + col_l*256 + ((g ^ (col_l & 63))<<2)) = pk;
      }
    }
    __syncthreads();
    const int half = lane >> 5, l32 = lane & 31;
    #pragma unroll
    for (int ps=0; ps<16; ps++){
      const int R = ps*16 + wid*2 + half;
      const int u0 = ((l32<<1)    ) ^ (R & 63);
      const int u1 = ((l32<<1) | 1) ^ (R & 63);
      ushort4 a = *(const ushort4*)(lt + R*256 + (u0<<2));
      ushort4 b = *(const ushort4*)(lt + R*256 + (u1<<2));
      u16* dst = Cz + (n0 + R)*(long)ldc + m0 + (l32<<3);
      *(ushort4*)dst = a;
      *(ushort4*)(dst+4) = b;
    }
  }
}

// ---------------------------------------------------------------------------
// gemm128_deep: generic 128x128 BK=64 deep-pipelined GEMM (counted vmcnt(4),
// chunk-XOR swizzle, setprio), 4 waves, 64KB LDS, 2 blocks/CU, bx-grouped
// XCD mapping. EPI: 0 = bf16 store, 1 = bf16 store + bias + relu.
template<int EPI>
__global__ __launch_bounds__(256, 2) void gemm128_deep(
    const u16* __restrict__ A, const u16* __restrict__ Bt, u16* __restrict__ C,
    const float* __restrict__ bias, int K, int lda, int ldb, int ldc)
{
  extern __shared__ u16 pm[];
  const int L = blockIdx.x;
  const int xcd = L & 7;
  const int q = L >> 3;
  const int by = (q >> 2) + xcd*16;
  const int bx = q & 3;
  const long m0 = (long)by * 128, n0 = (long)bx * 128;

  const int t = threadIdx.x;
  const int lane = t & 63;
  const int w = t >> 6;
  const int wr = w >> 1, wc = w & 1;

  const int row0 = t >> 2;
  const int cs0  = (t & 3) ^ ((row0 >> 1) & 3);

  const u16* aB0 = A + (m0 + row0)*(long)lda + cs0*8;
  const u16* aB1 = aB0 + 64*(long)lda;
  const u16* bB0 = Bt + (n0 + row0)*(long)ldb + cs0*8;
  const u16* bB1 = bB0 + 64*(long)ldb;

  auto issueA = [&](int sub, long off){
    u16* d = pm + sub*4096 + t*8;
    gld16(aB0 + off, d);
    gld16(aB1 + off, d + 2048);
  };
  auto issueB = [&](int sub, long off){
    u16* d = pm + 16384 + sub*4096 + t*8;
    gld16(bB0 + off, d);
    gld16(bB1 + off, d + 2048);
  };

  const int frow = lane & 15;
  const int elemoff = (((lane>>4) ^ ((frow>>1)&3)) << 3);
  const int rAoff = (wr*64 + frow)*32 + elemoff;
  const int rBoff = (wc*64 + frow)*32 + elemoff;

  f32x4 acc[4][4] = {};

  issueA(0, 0);  issueB(0, 0);
  issueA(1, 32); issueB(1, 32);

  const int NT = K >> 6;
  for (int tl = 0; tl < NT; ++tl) {
    const int b = tl & 1;
    const int nb2 = b ^ 1;
    const bool lastT = (tl == NT-1);
    const long offN = (long)(tl+1)*64;

    asm volatile("s_waitcnt vmcnt(4)" ::: "memory");
    __builtin_amdgcn_s_barrier();
    __builtin_amdgcn_sched_barrier(0);

    {
      const u16* pA = pm + (b*2+0)*4096 + rAoff;
      const u16* pB = pm + 16384 + (b*2+0)*4096 + rBoff;
      bf16x8 bf[4];
      #pragma unroll
      for (int i=0;i<4;i++) bf[i] = *(const bf16x8*)(pB + i*512);
      {
        bf16x8 a[2];
        #pragma unroll
        for (int i=0;i<2;i++) a[i] = *(const bf16x8*)(pA + i*512);
        if (!lastT) issueA(nb2*2+0, offN);
        __builtin_amdgcn_s_setprio(1);
        #pragma unroll
        for (int mi=0;mi<2;mi++)
          #pragma unroll
          for (int ni=0;ni<4;ni++)
            acc[mi][ni] = __builtin_amdgcn_mfma_f32_16x16x32_bf16(a[mi], bf[ni], acc[mi][ni],0,0,0);
        __builtin_amdgcn_s_setprio(0);
      }
      {
        bf16x8 a[2];
        #pragma unroll
        for (int i=0;i<2;i++) a[i] = *(const bf16x8*)(pA + (2+i)*512);
        if (!lastT) issueB(nb2*2+0, offN);
        __builtin_amdgcn_s_setprio(1);
        #pragma unroll
        for (int mi=0;mi<2;mi++)
          #pragma unroll
          for (int ni=0;ni<4;ni++)
            acc[2+mi][ni] = __builtin_amdgcn_mfma_f32_16x16x32_bf16(a[mi], bf[ni], acc[2+mi][ni],0,0,0);
        __builtin_amdgcn_s_setprio(0);
      }
    }

    if (lastT) asm volatile("s_waitcnt vmcnt(0)" ::: "memory");
    else       asm volatile("s_waitcnt vmcnt(4)" ::: "memory");
    __builtin_amdgcn_s_barrier();
    __builtin_amdgcn_sched_barrier(0);

    {
      const u16* pA = pm + (b*2+1)*4096 + rAoff;
      const u16* pB = pm + 16384 + (b*2+1)*4096 + rBoff;
      bf16x8 bf[4];
      #pragma unroll
      for (int i=0;i<4;i++) bf[i] = *(const bf16x8*)(pB + i*512);
      {
        bf16x8 a[2];
        #pragma unroll
        for (int i=0;i<2;i++) a[i] = *(const bf16x8*)(pA + i*512);
        if (!lastT) issueA(nb2*2+1, offN + 32);
        __builtin_amdgcn_s_setprio(1);
        #pragma unroll
        for (int mi=0;mi<2;mi++)
          #pragma unroll
          for (int ni=0;ni<4;ni++)
            acc[mi][ni] = __builtin_amdgcn_mfma_f32_16x16x32_bf16(a[mi], bf[ni], acc[mi][ni],0,0,0);
        __builtin_amdgcn_s_setprio(0);
      }
      {
        bf16x8 a[2];
        #pragma unroll
        for (int i=0;i<2;i++) a[i] = *(const bf16x8*)(pA + (2+i)*512);
        if (!lastT) issueB(nb2*2+1, offN + 32);
        __builtin_amdgcn_s_setprio(1);
        #pragma unroll
        for (int mi=0;mi<2;mi++)
          #pragma unroll
          for (int ni=0;ni<4;ni++)
            acc[2+mi][ni] = __builtin_amdgcn_mfma_f32_16x16x32_bf16(a[mi], bf[ni], acc[2+mi][ni],0,0,0);
        __builtin_amdgcn_s_setprio(0);
      }
    }
  }

  const int crow0 = wr*64 + ((lane>>4)<<2);
  const int ccol0 = wc*64 + frow;
  #pragma unroll
  for (int mi=0;mi<4;mi++){
    #pragma unroll
    for (int ni=0;ni<4;ni++){
      long col = n0 + ccol0 + ni*16;
      float bv = (EPI==1) ? bias[col] : 0.0f;
      #pragma unroll
      for (int r=0;r<4;r++){
        long row = m0 + crow0 + mi*16 + r;
        float v = acc[mi][ni][r];
        if (EPI==1){ v += bv; v = v > 0.0f ? v : 0.0f; }
        C[row*(long)ldc + col] = f2bf(v);
      }
    }
  }
}

// ---------------------------------------------------------------------------
// pv5: 128x128 PV GEMM, deep-pipeline schedule, 4 waves, 64KB LDS, 2/CU.
// z -> XCD-pair clustering; 4 bx-blocks sharing a P panel consecutive on one XCD.
__global__ __launch_bounds__(256, 2) void pv5(
    const u16* __restrict__ P0, const u16* __restrict__ P1,
    const u16* __restrict__ P2, const u16* __restrict__ P3,
    const u16* __restrict__ xT, u16* __restrict__ attb)
{
  extern __shared__ u16 pm[];
  const int L = blockIdx.x;
  const int xcd = L & 7;
  const int z = xcd >> 1;
  const int q = L >> 3;
  const int by = ((q >> 2) << 1) + (xcd & 1);
  const int bx = q & 3;
  const long ZS = 4096L*512;
  const u16* A  = (z==0)?P0:(z==1)?P1:(z==2)?P2:P3;
  const u16* Bt = xT   + (long)z*ZS;
  u16*       C  = attb + (long)z*ZS;
  const long m0 = (long)by * 128, n0 = (long)bx * 128;

  const int t = threadIdx.x;
  const int lane = t & 63;
  const int w = t >> 6;
  const int wr = w >> 1, wc = w & 1;

  const int row0 = t >> 2;
  const int cs0  = (t & 3) ^ ((row0 >> 1) & 3);

  const u16* aB0 = A + (m0 + row0)*4096L + cs0*8;
  const u16* aB1 = aB0 + 64*4096L;
  const u16* bB0 = Bt + (n0 + row0)*4096L + cs0*8;
  const u16* bB1 = bB0 + 64*4096L;

  auto issueA = [&](int sub, long off){
    u16* d = pm + sub*4096 + t*8;
    gld16(aB0 + off, d);
    gld16(aB1 + off, d + 2048);
  };
  auto issueB = [&](int sub, long off){
    u16* d = pm + 16384 + sub*4096 + t*8;
    gld16(bB0 + off, d);
    gld16(bB1 + off, d + 2048);
  };

  const int frow = lane & 15;
  const int elemoff = (((lane>>4) ^ ((frow>>1)&3)) << 3);
  const int rAoff = (wr*64 + frow)*32 + elemoff;
  const int rBoff = (wc*64 + frow)*32 + elemoff;

  f32x4 acc[4][4] = {};

  issueA(0, 0);  issueB(0, 0);
  issueA(1, 32); issueB(1, 32);

  const int NT = 64;
  for (int tl = 0; tl < NT; ++tl) {
    const int b = tl & 1;
    const int nb2 = b ^ 1;
    const bool lastT = (tl == NT-1);
    const long offN = (long)(tl+1)*64;

    asm volatile("s_waitcnt vmcnt(4)" ::: "memory");
    __builtin_amdgcn_s_barrier();
    __builtin_amdgcn_sched_barrier(0);

    {
      const u16* pA = pm + (b*2+0)*4096 + rAoff;
      const u16* pB = pm + 16384 + (b*2+0)*4096 + rBoff;
      bf16x8 bf[4];
      #pragma unroll
      for (int i=0;i<4;i++) bf[i] = *(const bf16x8*)(pB + i*512);
      {
        bf16x8 a[2];
        #pragma unroll
        for (int i=0;i<2;i++) a[i] = *(const bf16x8*)(pA + i*512);
        if (!lastT) issueA(nb2*2+0, offN);
        __builtin_amdgcn_s_setprio(1);
        #pragma unroll
        for (int mi=0;mi<2;mi++)
          #pragma unroll
          for (int ni=0;ni<4;ni++)
            acc[mi][ni] = __builtin_amdgcn_mfma_f32_16x16x32_bf16(a[mi], bf[ni], acc[mi][ni],0,0,0);
        __builtin_amdgcn_s_setprio(0);
      }
      {
        bf16x8 a[2];
        #pragma unroll
        for (int i=0;i<2;i++) a[i] = *(const bf16x8*)(pA + (2+i)*512);
        if (!lastT) issueB(nb2*2+0, offN);
        __builtin_amdgcn_s_setprio(1);
        #pragma unroll
        for (int mi=0;mi<2;mi++)
          #pragma unroll
          for (int ni=0;ni<4;ni++)
            acc[2+mi][ni] = __builtin_amdgcn_mfma_f32_16x16x32_bf16(a[mi], bf[ni], acc[2+mi][ni],0,0,0);
        __builtin_amdgcn_s_setprio(0);
      }
    }

    if (lastT) asm volatile("s_waitcnt vmcnt(0)" ::: "memory");
    else       asm volatile("s_waitcnt vmcnt(4)" ::: "memory");
    __builtin_amdgcn_s_barrier();
    __builtin_amdgcn_sched_barrier(0);

    {
      const u16* pA = pm + (b*2+1)*4096 + rAoff;
      const u16* pB = pm + 16384 + (b*2+1)*4096 + rBoff;
      bf16x8 bf[4];
      #pragma unroll
      for (int i=0;i<4;i++) bf[i] = *(const bf16x8*)(pB + i*512);
      {
        bf16x8 a[2];
        #pragma unroll
        for (int i=0;i<2;i++) a[i] = *(const bf16x8*)(pA + i*512);
        if (!lastT) issueA(nb2*2+1, offN + 32);
        __builtin_amdgcn_s_setprio(1);
        #pragma unroll
        for (int mi=0;mi<2;mi++)
          #pragma unroll
          for (int ni=0;ni<4;ni++)
            acc[mi][ni] = __builtin_amdgcn_mfma_f32_16x16x32_bf16(a[mi], bf[ni], acc[mi][ni],0,0,0);
        __builtin_amdgcn_s_setprio(0);
      }
      {
        bf16x8 a[2];
        #pragma unroll
        for (int i=0;i<2;i++) a[i] = *(const bf16x8*)(pA + (2+i)*512);
        if (!lastT) issueB(nb2*2+1, offN + 32);
        __builtin_amdgcn_s_setprio(1);
        #pragma unroll
        for (int mi=0;mi<2;mi++)
          #pragma unroll
          for (int ni=0;ni<4;ni++)
            acc[2+mi][ni] = __builtin_amdgcn_mfma_f32_16x16x32_bf16(a[mi], bf[ni], acc[2+mi][ni],0,0,0);
        __builtin_amdgcn_s_setprio(0);
      }
    }
  }

  const int crow0 = wr*64 + ((lane>>4)<<2);
  const int ccol0 = wc*64 + frow;
  #pragma unroll
  for (int mi=0;mi<4;mi++){
    #pragma unroll
    for (int ni=0;ni<4;ni++){
      long col = n0 + ccol0 + ni*16;
      #pragma unroll
      for (int r=0;r<4;r++){
        long row = m0 + crow0 + mi*16 + r;
        C[row*512 + col] = f2bf(acc[mi][ni][r]);
      }
    }
  }
}

// ---------------------------------------------------------------------------
// Batched in-place row softmax: 4 z-planes. fp16 shifted logits -> bf16 P.
__global__ __launch_bounds__(256) void softmax_batched(
    u16* __restrict__ S0, u16* __restrict__ S1,
    u16* __restrict__ S2, u16* __restrict__ S3)
{
  const int z = blockIdx.x >> 12;
  const long row = blockIdx.x & 4095;
  u16* buf = (z==0)?S0:(z==1)?S1:(z==2)?S2:S3;
  u16* src = buf + row*4096;
  const int t = threadIdx.x, lane = t&63, w = t>>6;
  float v[16];
  #pragma unroll
  for (int i=0;i<2;i++){
    u16x8 q = *(const u16x8*)(src + t*16 + i*8);
    #pragma unroll
    for (int j=0;j<8;j++) v[i*8+j] = h2f(q[j]);
  }
  float mx = v[0];
  #pragma unroll
  for (int i=1;i<16;i++) mx = fmaxf(mx, v[i]);
  #pragma unroll
  for (int off=32; off; off>>=1) mx = fmaxf(mx, __shfl_xor(mx, off));
  __shared__ float red[4];
  if (lane==0) red[w] = mx;
  __syncthreads();
  mx = fmaxf(fmaxf(red[0],red[1]), fmaxf(red[2],red[3]));
  float sum = 0.0f;
  #pragma unroll
  for (int i=0;i<16;i++){ v[i] = __expf(v[i]-mx); sum += v[i]; }
  #pragma unroll
  for (int off=32; off; off>>=1) sum += __shfl_xor(sum, off);
  __shared__ float red2[4];
  if (lane==0) red2[w] = sum;
  __syncthreads();
  sum = red2[0]+red2[1]+red2[2]+red2[3];
  const float inv = 1.0f/sum;
  #pragma unroll
  for (int i=0;i<2;i++){
    u16x8 o;
    #pragma unroll
    for (int j=0;j<8;j++) o[j] = f2bf(v[i*8+j]*inv);
    *(u16x8*)(src + t*16 + i*8) = o;
  }
}

// Row LayerNorm over 512 (optional residual add), bf16 out
template<int ADD>
__global__ __launch_bounds__(256) void ln_row(
    const u16* __restrict__ X, const u16* __restrict__ Y,
    const float* __restrict__ w, const float* __restrict__ b,
    u16* __restrict__ outB)
{
  const long row = blockIdx.x;
  const int t = threadIdx.x, lane = t&63, wv = t>>6;
  ushort2 xv = *(const ushort2*)(X + row*512 + t*2);
  float v0 = bf2f(xv.x), v1 = bf2f(xv.y);
  if (ADD){
    ushort2 yv = *(const ushort2*)(Y + row*512 + t*2);
    v0 += bf2f(yv.x); v1 += bf2f(yv.y);
  }
  float s = v0+v1, q = v0*v0 + v1*v1;
  #pragma unroll
  for (int off=32; off; off>>=1){ s += __shfl_xor(s,off); q += __shfl_xor(q,off); }
  __shared__ float red[8];
  if (lane==0){ red[wv]=s; red[4+wv]=q; }
  __syncthreads();
  s = red[0]+red[1]+red[2]+red[3];
  q = red[4]+red[5]+red[6]+red[7];
  const float u = s*(1.0f/512.0f);
  const float var = q*(1.0f/512.0f) - u*u;
  const float inv = rsqrtf(var + 1e-12f);
  const int c = t*2;
  float o0 = (v0-u)*inv*w[c]   + b[c];
  float o1 = (v1-u)*inv*w[c+1] + b[c+1];
  ushort2 ov; ov.x=f2bf(o0); ov.y=f2bf(o1);
  *(ushort2*)(outB + row*512 + c) = ov;
}

// ---------------------------------------------------------------------------
extern "C" void kernel_launch(void* const* d_in, const int* in_sizes, int n_in,
                              void* d_out, int out_size, void* d_ws, size_t ws_size,
                              hipStream_t stream) {
  const float* T1   = (const float*)d_in[0];
  const float* T2   = (const float*)d_in[1];
  const float* w3   = (const float*)d_in[2];
  const float* w1   = (const float*)d_in[3];
  const float* bg   = (const float*)d_in[4];
  const float* bb   = (const float*)d_in[5];
  const float* bm   = (const float*)d_in[6];
  const float* bv   = (const float*)d_in[7];
  const float* ln1w = (const float*)d_in[8];
  const float* ln1b = (const float*)d_in[9];
  const float* linw = (const float*)d_in[10];
  const float* linb = (const float*)d_in[11];
  const float* ln2w = (const float*)d_in[12];
  const float* ln2b = (const float*)d_in[13];

  hipFuncSetAttribute(reinterpret_cast<const void*>(gemm256<0,1>),
                      hipFuncAttributeMaxDynamicSharedMemorySize, 131072);
  hipFuncSetAttribute(reinterpret_cast<const void*>(gemm256<3,0>),
                      hipFuncAttributeMaxDynamicSharedMemorySize, 131072);
  hipFuncSetAttribute(reinterpret_cast<const void*>(pv5),
                      hipFuncAttributeMaxDynamicSharedMemorySize, 65536);
  hipFuncSetAttribute(reinterpret_cast<const void*>(gemm128_deep<0>),
                      hipFuncAttributeMaxDynamicSharedMemorySize, 65536);
  hipFuncSetAttribute(reinterpret_cast<const void*>(gemm128_deep<1>),
                      hipFuncAttributeMaxDynamicSharedMemorySize, 65536);

  char* ws = (char*)d_ws;
  size_t off = 0;
  auto alloc = [&](size_t bytes)->char* {
    char* p = ws + off;
    off += (bytes + 255) & ~(size_t)255;
    return p;
  };
  const size_t XPAD_B = 4L*66*66*1024*2;
  u16*   Xpad  = (u16*)  alloc(XPAD_B);               // aliased as S3 after conv3
  u16*   wk3t  = (u16*)  alloc(1024L*9216*2);
  u16*   w1t   = (u16*)  alloc(512L*1024*2);
  u16*   lint  = (u16*)  alloc(512L*512*2);
  float* bias1 = (float*)alloc(512*4);
  float* nrm   = (float*)alloc(16384L*4);
  u16*   Y1    = (u16*)  alloc(16384L*1024*2);        // aliased as S0 after conv1
  u16*   x0    = (u16*)  alloc(16384L*512*2);         // reused as final bf16 buf
  u16*   xT    = (u16*)  alloc(4L*512*4096*2);
  u16*   Sreg  = (u16*)  alloc(2L*4096*4096*2);       // S1 (lower) + S2 (upper)
  u16*   attb  = (u16*)  alloc(16384L*512*2);
  u16*   h     = (u16*)  alloc(16384L*512*2);
  u16*   g     = (u16*)  alloc(16384L*512*2);
  u16*   rel1  = (u16*)  alloc(16384L*512*2);
  u16*   S0    = Y1;
  u16*   S1    = Sreg;
  u16*   S2    = Sreg + 4096L*4096;
  u16*   S3    = Xpad;
  if (off > ws_size) return;  // workspace too small -> visible failure

  const long ZS = 4096L*512;

  // --- prep ---
  border_zero<<<dim3(260,4), 256, 0, stream>>>(Xpad);
  pad_interior<<<dim3(64,16,4), 256, 0, stream>>>(T1, T2, Xpad);
  prep_w3<<<1024, 256, 0, stream>>>(w3, wk3t);
  prep_small<<<3074, 256, 0, stream>>>(w1, bg, bb, bm, bv, linw, w1t, lint, bias1);

  // --- conv3x3 -> Y1 ; conv1x1+BN+ReLU -> x0 ---
  gemm256<0,1><<<dim3(4,64), 512, 131072, stream>>>(Xpad, wk3t, (void*)Y1, 9216, 0, 9216, 1024,
                                                    nullptr, nullptr, nullptr, nullptr, nullptr);
  gemm128_deep<1><<<512, 256, 65536, stream>>>(Y1, w1t, x0, bias1, 1024, 1024, 1024, 512);

  // --- attention: symmetric batched S-GEMM, batched in-place softmax, pv5 ---
  auto attend = [&](const u16* xin){
    transpose_bf<<<dim3(64,8,4), 256, 0, stream>>>(xin, xT, 4096, 512, ZS, ZS);
    row_norm<<<4096, 256, 0, stream>>>(xin, nrm);
    gemm256<3,0><<<dim3(544), 512, 131072, stream>>>(xin, xin, nullptr, 512, 512, 512, 4096,
                                                     nrm, S0, S1, S2, S3);
    softmax_batched<<<16384, 256, 0, stream>>>(S0, S1, S2, S3);
    pv5<<<512, 256, 65536, stream>>>(S0, S1, S2, S3, xT, attb);
  };

  // --- block 1 ---
  attend(x0);
  ln_row<1><<<16384, 256, 0, stream>>>(x0, attb, ln1w, ln1b, h);
  gemm128_deep<1><<<512, 256, 65536, stream>>>(h, lint, g, linb, 512, 512, 512, 512);
  ln_row<0><<<16384, 256, 0, stream>>>(g, nullptr, ln2w, ln2b, rel1);

  // --- block 2 (same params) ---
  attend(rel1);
  ln_row<1><<<16384, 256, 0, stream>>>(rel1, attb, ln1w, ln1b, h);
  gemm128_deep<1><<<512, 256, 65536, stream>>>(h, lint, g, linb, 512, 512, 512, 512);
  ln_row<0><<<16384, 256, 0, stream>>>(g, nullptr, ln2w, ln2b, x0);

  // --- final NHWC bf16 -> NCHW f32 ---
  transpose_bf_f32<<<dim3(64,8,4), 256, 0, stream>>>(x0, (float*)d_out);
}

// Round 13
// 794.866 us; speedup vs baseline: 1.0387x; 1.0387x over previous
//
#include <hip/hip_runtime.h>
#include <stdint.h>

typedef float f32x4 __attribute__((ext_vector_type(4)));
typedef __bf16 bf16x8 __attribute__((ext_vector_type(8)));
typedef unsigned short u16;
typedef unsigned short u16x8 __attribute__((ext_vector_type(8)));

__device__ __forceinline__ float bf2f(u16 u){ unsigned int i = ((unsigned int)u)<<16; float f; __builtin_memcpy(&f,&i,4); return f; }
__device__ __forceinline__ u16 f2bf(float f){ unsigned int i; __builtin_memcpy(&i,&f,4); i += 0x7FFFu + ((i>>16)&1u); return (u16)(i>>16); }
__device__ __forceinline__ u16 f2h(float f){ _Float16 h = (_Float16)f; u16 b; __builtin_memcpy(&b,&h,2); return b; }
__device__ __forceinline__ float h2f(u16 b){ _Float16 h; __builtin_memcpy(&h,&b,2); return (float)h; }

__device__ __forceinline__ void gld16(const void* g, void* l){
  __builtin_amdgcn_global_load_lds(
      (const __attribute__((address_space(1))) void*)(uintptr_t)g,
      (__attribute__((address_space(3))) void*)(unsigned int)(uintptr_t)l, 16, 0, 0);
}

// ---------------------------------------------------------------------------
// Zero only the border pixels of Xpad [4][66][66][1024] (interior fully
// rewritten by pad_interior each call; S3 aliasing clobbers borders between
// calls, so borders must be re-zeroed per call).
__global__ __launch_bounds__(256) void border_zero(u16* __restrict__ Xpad){
  const int n = blockIdx.y, p = blockIdx.x;   // p in 0..259
  int y, x;
  if (p < 66)        { y = 0;        x = p; }
  else if (p < 132)  { y = 65;       x = p - 66; }
  else if (p < 196)  { y = p - 131;  x = 0; }     // y = 1..64
  else               { y = p - 195;  x = 65; }    // y = 1..64
  ushort4 z = {0,0,0,0};
  *(ushort4*)(Xpad + (((long)n*66 + y)*66 + x)*1024 + threadIdx.x*4) = z;
}

// Prep: concat(T1,T2) NCHW f32 -> Xpad interior bf16.
__global__ __launch_bounds__(256) void pad_interior(const float* __restrict__ T1,
                                                    const float* __restrict__ T2,
                                                    u16* __restrict__ Xpad){
  const int n = blockIdx.z, ct = blockIdx.y, pt = blockIdx.x;
  const int t = threadIdx.x;
  const int c0 = ct*64, p0 = pt*64;
  const float* src = (c0 < 512) ? (T1 + ((long)n*512 + c0)*4096)
                                : (T2 + ((long)n*512 + (c0-512))*4096);
  __shared__ u16 lds[64][66];
  #pragma unroll
  for (int i=0;i<4;i++){
    int c = i*16 + (t>>4);
    int ch = t&15;
    float4 v = *(const float4*)(src + (long)c*4096 + p0 + ch*4);
    int p = ch*4;
    lds[p+0][c] = f2bf(v.x); lds[p+1][c] = f2bf(v.y);
    lds[p+2][c] = f2bf(v.z); lds[p+3][c] = f2bf(v.w);
  }
  __syncthreads();
  #pragma unroll
  for (int i=0;i<8;i++){
    int p = i*8 + (t>>5);
    int c2 = t&31;
    int pix = p0 + p; int yy = (pix>>6)+1, xx = (pix&63)+1;
    ushort2 val; val.x = lds[p][2*c2]; val.y = lds[p][2*c2+1];
    *(ushort2*)(Xpad + (((long)n*66 + yy)*66 + xx)*1024 + c0 + 2*c2) = val;
  }
}

// w_conv3 [o][ci][3][3] f32 -> wk3t [o][tap][ci] bf16
__global__ __launch_bounds__(256) void prep_w3(const float* __restrict__ w3, u16* __restrict__ wk3t){
  const int o = blockIdx.x; const int t = threadIdx.x;
  __shared__ u16 lds[9216];
  const float* src = w3 + (long)o*9216;
  #pragma unroll
  for (int i=0;i<9;i++){
    int j = i*256 + t;
    float4 v = *(const float4*)(src + j*4);
    lds[j*4+0]=f2bf(v.x); lds[j*4+1]=f2bf(v.y); lds[j*4+2]=f2bf(v.z); lds[j*4+3]=f2bf(v.w);
  }
  __syncthreads();
  u16* dst = wk3t + (long)o*9216;
  #pragma unroll
  for (int i=0;i<36;i++){
    int j = i*256 + t; int tp = j>>10, ci = j&1023;
    dst[j] = lds[ci*9+tp];
  }
}

// merged small prep: w1t (2048 blocks), lint (1024 blocks), bias1 (2 blocks)
__global__ void prep_small(const float* __restrict__ w1, const float* __restrict__ bg,
                           const float* __restrict__ bb, const float* __restrict__ bm,
                           const float* __restrict__ bv, const float* __restrict__ linw,
                           u16* __restrict__ w1t, u16* __restrict__ lint,
                           float* __restrict__ bias1){
  const int b = blockIdx.x, t = threadIdx.x;
  if (b < 2048){
    long i = (long)b*256 + t;
    int o = (int)(i>>10);
    float inv = bg[o] / sqrtf(bv[o] + 1e-5f);
    w1t[i] = f2bf(w1[i]*inv);
  } else if (b < 3072){
    long i = (long)(b-2048)*256 + t;
    lint[i] = f2bf(linw[i]);
  } else {
    int o = (b-3072)*256 + t;
    float inv = bg[o]/sqrtf(bv[o]+1e-5f);
    bias1[o] = bb[o] - bm[o]*inv;
  }
}

// per-row squared norm of bf16 [rows][512] -> f32 (softmax shift reference)
__global__ __launch_bounds__(256) void row_norm(const u16* __restrict__ x, float* __restrict__ nrm){
  const int row = blockIdx.x*4 + (threadIdx.x>>6);
  const int lane = threadIdx.x & 63;
  u16x8 q = *(const u16x8*)(x + (long)row*512 + lane*8);
  float s = 0.f;
  #pragma unroll
  for (int j=0;j<8;j++){ float f = bf2f(q[j]); s += f*f; }
  #pragma unroll
  for (int off=32; off; off>>=1) s += __shfl_xor(s, off);
  if (lane==0) nrm[row] = s;
}

// bf16 transpose: dst[c][r] = src[r][c], tiles 64x64
__global__ __launch_bounds__(256) void transpose_bf(const u16* __restrict__ src, u16* __restrict__ dst,
                                                    int R, int C, long sStr, long dStr){
  const int z = blockIdx.z;
  src += (long)z*sStr; dst += (long)z*dStr;
  const int r0 = blockIdx.x*64, c0 = blockIdx.y*64;
  const int t = threadIdx.x;
  __shared__ u16 lds[64][66];
  #pragma unroll
  for (int i=0;i<4;i++){
    int r = i*16 + (t>>4), ch = t&15;
    ushort4 v = *(const ushort4*)(src + (long)(r0+r)*C + c0 + ch*4);
    lds[r][ch*4+0]=v.x; lds[r][ch*4+1]=v.y; lds[r][ch*4+2]=v.z; lds[r][ch*4+3]=v.w;
  }
  __syncthreads();
  #pragma unroll
  for (int i=0;i<4;i++){
    int c = i*16 + (t>>4), ch = t&15;
    ushort4 v;
    v.x = lds[ch*4+0][c]; v.y = lds[ch*4+1][c]; v.z = lds[ch*4+2][c]; v.w = lds[ch*4+3][c];
    *(ushort4*)(dst + (long)(c0+c)*R + r0 + ch*4) = v;
  }
}

// bf16 [4096][512] -> f32 NCHW [512][4096] transpose (final output)
__global__ __launch_bounds__(256) void transpose_bf_f32(const u16* __restrict__ src, float* __restrict__ dst){
  const int z = blockIdx.z;
  src += (long)z*4096*512; dst += (long)z*512*4096;
  const int r0 = blockIdx.x*64, c0 = blockIdx.y*64;
  const int t = threadIdx.x;
  __shared__ u16 lds[64][66];
  #pragma unroll
  for (int i=0;i<4;i++){
    int r = i*16 + (t>>4), ch = t&15;
    ushort4 v = *(const ushort4*)(src + (long)(r0+r)*512 + c0 + ch*4);
    lds[r][ch*4+0]=v.x; lds[r][ch*4+1]=v.y; lds[r][ch*4+2]=v.z; lds[r][ch*4+3]=v.w;
  }
  __syncthreads();
  #pragma unroll
  for (int i=0;i<4;i++){
    int c = i*16 + (t>>4), ch = t&15;
    float4 v;
    v.x = bf2f(lds[ch*4+0][c]); v.y = bf2f(lds[ch*4+1][c]);
    v.z = bf2f(lds[ch*4+2][c]); v.w = bf2f(lds[ch*4+3][c]);
    *(float4*)(dst + (long)(c0+c)*4096 + r0 + ch*4) = v;
  }
}

// ---------------------------------------------------------------------------
// 256x256 deep-pipelined bf16 MFMA GEMM (B^T convention), BK=64, 8 waves.
// Two-wait interleaved schedule (R11): K-half sub-staging [A.k0,B.k0,A.k1,B.k1],
// counted vmcnt(4), loads issued inside MFMA phases, 2 barriers/tile.
// EPI 0: bf16 store (conv3). EPI 3: SYMMETRIC batched S = x.x^T (544 blocks,
// upper-tri; off-diag writes transposed tile via LDS reuse, bit-identical).
template<int EPI, int CONV>
__global__ __launch_bounds__(512, 2) void gemm256(
    const u16* __restrict__ Ain, const u16* __restrict__ Btin, void* __restrict__ Cv,
    int K, int lda, int ldb, int ldc, const float* __restrict__ srowIn,
    u16* __restrict__ C0, u16* __restrict__ C1, u16* __restrict__ C2, u16* __restrict__ C3)
{
  extern __shared__ u16 sm[];
  const int t = threadIdx.x;
  const int lane = t & 63;
  const int wid = t >> 6;
  const int wr = wid >> 2, wc = wid & 3;

  long m0, n0;
  int byv = 0, bxv = 0;
  const u16* A; const u16* Bt; const float* srow; u16* Cz;
  if (EPI == 3){
    const int orig = blockIdx.x;                 // 544 blocks
    const int swz = (orig & 7) * 68 + (orig >> 3);
    const int z = swz / 136;
    int p = swz % 136;
    int by = 0;
    while (p >= 16 - by){ p -= 16 - by; by++; }
    const int bx = by + p;                       // by <= bx
    byv = by; bxv = bx;
    m0 = (long)by * 256; n0 = (long)bx * 256;
    A = Ain + (long)z*4096*lda;
    Bt = A;
    srow = srowIn + (long)z*4096;
    Cz = (z==0)?C0:(z==1)?C1:(z==2)?C2:C3;
  } else {
    const int orig = blockIdx.y * gridDim.x + blockIdx.x;
    const int cpx = (gridDim.x * gridDim.y) >> 3;
    const int swz = (orig & 7) * cpx + (orig >> 3);
    const int bx = swz % gridDim.x;
    const int by = swz / gridDim.x;
    m0 = (long)by * 256; n0 = (long)bx * 256;
    A = Ain; Bt = Btin; srow = srowIn; Cz = (u16*)Cv;
  }

  const int row0 = t >> 2;
  const int cs0  = (t & 3) ^ ((row0 >> 1) & 3);

  const u16 *aB0, *aB1;
  if (CONV) {
    long m_ = m0 + row0;
    long pb0 = ((long)((int)(m_>>12)*66 + (int)((m_>>6)&63)))*66 + (int)(m_&63);
    m_ = m0 + row0 + 128;
    long pb1 = ((long)((int)(m_>>12)*66 + (int)((m_>>6)&63)))*66 + (int)(m_&63);
    aB0 = A + pb0*1024 + cs0*8;
    aB1 = A + pb1*1024 + cs0*8;
  } else {
    aB0 = A + (m0 + row0)*(long)lda + cs0*8;
    aB1 = A + (m0 + row0 + 128)*(long)lda + cs0*8;
  }
  const u16* bB0 = Bt + (n0 + row0)*(long)ldb + cs0*8;
  const u16* bB1 = Bt + (n0 + row0 + 128)*(long)ldb + cs0*8;

  auto issueA = [&](int sub, long aoff){
    u16* d = sm + sub*8192 + t*8;
    gld16(aB0 + aoff, d);
    gld16(aB1 + aoff, d + 4096);
  };
  auto issueB = [&](int sub, long boff){
    u16* d = sm + 32768 + sub*8192 + t*8;
    gld16(bB0 + boff, d);
    gld16(bB1 + boff, d + 4096);
  };
  auto conv_aoff = [&](int tile)->long {
    int kb = tile << 6;
    int tap = kb >> 10;
    int cb  = kb & 1023;
    int ky = (tap >= 6) ? 2 : (tap >= 3 ? 1 : 0);
    int kx = tap - ky*3;
    return (long)(ky*66 + kx)*1024 + cb;
  };

  const int frow = lane & 15;
  const int elemoff = (((lane>>4) ^ ((frow>>1)&3)) << 3);
  const int rAoff = (wr*128 + frow)*32 + elemoff;
  const int rBoff = (wc*64  + frow)*32 + elemoff;

  f32x4 acc[8][4] = {};

  {
    long a0 = CONV ? conv_aoff(0) : 0L;
    issueA(0, a0);
    issueB(0, 0);
    issueA(1, a0 + 32);
    issueB(1, 32);
  }

  const int NT = K >> 6;
  for (int tile = 0; tile < NT; ++tile) {
    const int b = tile & 1;
    const int nb2 = b ^ 1;
    const bool lastT = (tile == NT-1);
    long aoffN = 0, boffN = 0;
    if (!lastT) {
      aoffN = CONV ? conv_aoff(tile+1) : (long)(tile+1)*64;
      boffN = (long)(tile+1)*64;
    }

    asm volatile("s_waitcnt vmcnt(4)" ::: "memory");
    __builtin_amdgcn_s_barrier();
    __builtin_amdgcn_sched_barrier(0);

    {
      const u16* pA = sm + (b*2+0)*8192 + rAoff;
      const u16* pB = sm + 32768 + (b*2+0)*8192 + rBoff;
      bf16x8 bf[4];
      #pragma unroll
      for (int i=0;i<4;i++) bf[i] = *(const bf16x8*)(pB + i*512);
      {
        bf16x8 a[4];
        #pragma unroll
        for (int i=0;i<4;i++) a[i] = *(const bf16x8*)(pA + i*512);
        if (!lastT) issueA(nb2*2+0, aoffN);
        __builtin_amdgcn_s_setprio(1);
        #pragma unroll
        for (int mi=0;mi<4;mi++)
          #pragma unroll
          for (int ni=0;ni<4;ni++)
            acc[mi][ni] = __builtin_amdgcn_mfma_f32_16x16x32_bf16(a[mi], bf[ni], acc[mi][ni],0,0,0);
        __builtin_amdgcn_s_setprio(0);
      }
      {
        bf16x8 a[4];
        #pragma unroll
        for (int i=0;i<4;i++) a[i] = *(const bf16x8*)(pA + (4+i)*512);
        if (!lastT) issueB(nb2*2+0, boffN);
        __builtin_amdgcn_s_setprio(1);
        #pragma unroll
        for (int mi=0;mi<4;mi++)
          #pragma unroll
          for (int ni=0;ni<4;ni++)
            acc[4+mi][ni] = __builtin_amdgcn_mfma_f32_16x16x32_bf16(a[mi], bf[ni], acc[4+mi][ni],0,0,0);
        __builtin_amdgcn_s_setprio(0);
      }
    }

    if (lastT) asm volatile("s_waitcnt vmcnt(0)" ::: "memory");
    else       asm volatile("s_waitcnt vmcnt(4)" ::: "memory");
    __builtin_amdgcn_s_barrier();
    __builtin_amdgcn_sched_barrier(0);

    {
      const u16* pA = sm + (b*2+1)*8192 + rAoff;
      const u16* pB = sm + 32768 + (b*2+1)*8192 + rBoff;
      bf16x8 bf[4];
      #pragma unroll
      for (int i=0;i<4;i++) bf[i] = *(const bf16x8*)(pB + i*512);
      {
        bf16x8 a[4];
        #pragma unroll
        for (int i=0;i<4;i++) a[i] = *(const bf16x8*)(pA + i*512);
        if (!lastT) issueA(nb2*2+1, aoffN + 32);
        __builtin_amdgcn_s_setprio(1);
        #pragma unroll
        for (int mi=0;mi<4;mi++)
          #pragma unroll
          for (int ni=0;ni<4;ni++)
            acc[mi][ni] = __builtin_amdgcn_mfma_f32_16x16x32_bf16(a[mi], bf[ni], acc[mi][ni],0,0,0);
        __builtin_amdgcn_s_setprio(0);
      }
      {
        bf16x8 a[4];
        #pragma unroll
        for (int i=0;i<4;i++) a[i] = *(const bf16x8*)(pA + (4+i)*512);
        if (!lastT) issueB(nb2*2+1, boffN + 32);
        __builtin_amdgcn_s_setprio(1);
        #pragma unroll
        for (int mi=0;mi<4;mi++)
          #pragma unroll
          for (int ni=0;ni<4;ni++)
            acc[4+mi][ni] = __builtin_amdgcn_mfma_f32_16x16x32_bf16(a[mi], bf[ni], acc[4+mi][ni],0,0,0);
        __builtin_amdgcn_s_setprio(0);
      }
    }
  }

  const int crow0 = wr*128 + ((lane>>4)<<2);
  const int ccol0 = wc*64 + frow;

  #pragma unroll
  for (int mi=0;mi<8;mi++){
    #pragma unroll
    for (int ni=0;ni<4;ni++){
      long col = n0 + ccol0 + ni*16;
      #pragma unroll
      for (int r=0;r<4;r++){
        long row = m0 + crow0 + mi*16 + r;
        float v = acc[mi][ni][r];
        if (EPI==3) Cz[row*(long)ldc + col] = f2h(v - srow[row]);
        else        Cz[row*(long)ldc + col] = f2bf(v);
      }
    }
  }

  if (EPI == 3 && bxv != byv){
    __syncthreads();
    u16* lt = sm;
    float sc[4];
    #pragma unroll
    for (int ni=0;ni<4;ni++) sc[ni] = srow[n0 + ccol0 + ni*16];
    #pragma unroll
    for (int mi=0;mi<8;mi++){
      const int g = (crow0 + mi*16) >> 2;
      #pragma unroll
      for (int ni=0;ni<4;ni++){
        const int col_l = ccol0 + ni*16;
        ushort4 pk;
        #pragma unroll
        for (int r=0;r<4;r++) pk[r] = f2h(acc[mi][ni][r] - sc[ni]);
        *(ushort4*)(lt + col_l*256 + ((g ^ (col_l & 63))<<2)) = pk;
      }
    }
    __syncthreads();
    const int half = lane >> 5, l32 = lane & 31;
    #pragma unroll
    for (int ps=0; ps<16; ps++){
      const int R = ps*16 + wid*2 + half;
      const int u0 = ((l32<<1)    ) ^ (R & 63);
      const int u1 = ((l32<<1) | 1) ^ (R & 63);
      ushort4 a = *(const ushort4*)(lt + R*256 + (u0<<2));
      ushort4 b = *(const ushort4*)(lt + R*256 + (u1<<2));
      u16* dst = Cz + (n0 + R)*(long)ldc + m0 + (l32<<3);
      *(ushort4*)dst = a;
      *(ushort4*)(dst+4) = b;
    }
  }
}

// ---------------------------------------------------------------------------
// gemm128_deep: generic 128x128 BK=64 deep-pipelined GEMM (counted vmcnt(4),
// chunk-XOR swizzle, setprio), 4 waves, 64KB LDS, 2 blocks/CU, bx-grouped
// XCD mapping. EPI: 0 = bf16 store, 1 = bf16 store + bias + relu.
template<int EPI>
__global__ __launch_bounds__(256, 2) void gemm128_deep(
    const u16* __restrict__ A, const u16* __restrict__ Bt, u16* __restrict__ C,
    const float* __restrict__ bias, int K, int lda, int ldb, int ldc)
{
  extern __shared__ u16 pm[];
  const int L = blockIdx.x;
  const int xcd = L & 7;
  const int q = L >> 3;
  const int by = (q >> 2) + xcd*16;
  const int bx = q & 3;
  const long m0 = (long)by * 128, n0 = (long)bx * 128;

  const int t = threadIdx.x;
  const int lane = t & 63;
  const int w = t >> 6;
  const int wr = w >> 1, wc = w & 1;

  const int row0 = t >> 2;
  const int cs0  = (t & 3) ^ ((row0 >> 1) & 3);

  const u16* aB0 = A + (m0 + row0)*(long)lda + cs0*8;
  const u16* aB1 = aB0 + 64*(long)lda;
  const u16* bB0 = Bt + (n0 + row0)*(long)ldb + cs0*8;
  const u16* bB1 = bB0 + 64*(long)ldb;

  auto issueA = [&](int sub, long off){
    u16* d = pm + sub*4096 + t*8;
    gld16(aB0 + off, d);
    gld16(aB1 + off, d + 2048);
  };
  auto issueB = [&](int sub, long off){
    u16* d = pm + 16384 + sub*4096 + t*8;
    gld16(bB0 + off, d);
    gld16(bB1 + off, d + 2048);
  };

  const int frow = lane & 15;
  const int elemoff = (((lane>>4) ^ ((frow>>1)&3)) << 3);
  const int rAoff = (wr*64 + frow)*32 + elemoff;
  const int rBoff = (wc*64 + frow)*32 + elemoff;

  f32x4 acc[4][4] = {};

  issueA(0, 0);  issueB(0, 0);
  issueA(1, 32); issueB(1, 32);

  const int NT = K >> 6;
  for (int tl = 0; tl < NT; ++tl) {
    const int b = tl & 1;
    const int nb2 = b ^ 1;
    const bool lastT = (tl == NT-1);
    const long offN = (long)(tl+1)*64;

    asm volatile("s_waitcnt vmcnt(4)" ::: "memory");
    __builtin_amdgcn_s_barrier();
    __builtin_amdgcn_sched_barrier(0);

    {
      const u16* pA = pm + (b*2+0)*4096 + rAoff;
      const u16* pB = pm + 16384 + (b*2+0)*4096 + rBoff;
      bf16x8 bf[4];
      #pragma unroll
      for (int i=0;i<4;i++) bf[i] = *(const bf16x8*)(pB + i*512);
      {
        bf16x8 a[2];
        #pragma unroll
        for (int i=0;i<2;i++) a[i] = *(const bf16x8*)(pA + i*512);
        if (!lastT) issueA(nb2*2+0, offN);
        __builtin_amdgcn_s_setprio(1);
        #pragma unroll
        for (int mi=0;mi<2;mi++)
          #pragma unroll
          for (int ni=0;ni<4;ni++)
            acc[mi][ni] = __builtin_amdgcn_mfma_f32_16x16x32_bf16(a[mi], bf[ni], acc[mi][ni],0,0,0);
        __builtin_amdgcn_s_setprio(0);
      }
      {
        bf16x8 a[2];
        #pragma unroll
        for (int i=0;i<2;i++) a[i] = *(const bf16x8*)(pA + (2+i)*512);
        if (!lastT) issueB(nb2*2+0, offN);
        __builtin_amdgcn_s_setprio(1);
        #pragma unroll
        for (int mi=0;mi<2;mi++)
          #pragma unroll
          for (int ni=0;ni<4;ni++)
            acc[2+mi][ni] = __builtin_amdgcn_mfma_f32_16x16x32_bf16(a[mi], bf[ni], acc[2+mi][ni],0,0,0);
        __builtin_amdgcn_s_setprio(0);
      }
    }

    if (lastT) asm volatile("s_waitcnt vmcnt(0)" ::: "memory");
    else       asm volatile("s_waitcnt vmcnt(4)" ::: "memory");
    __builtin_amdgcn_s_barrier();
    __builtin_amdgcn_sched_barrier(0);

    {
      const u16* pA = pm + (b*2+1)*4096 + rAoff;
      const u16* pB = pm + 16384 + (b*2+1)*4096 + rBoff;
      bf16x8 bf[4];
      #pragma unroll
      for (int i=0;i<4;i++) bf[i] = *(const bf16x8*)(pB + i*512);
      {
        bf16x8 a[2];
        #pragma unroll
        for (int i=0;i<2;i++) a[i] = *(const bf16x8*)(pA + i*512);
        if (!lastT) issueA(nb2*2+1, offN + 32);
        __builtin_amdgcn_s_setprio(1);
        #pragma unroll
        for (int mi=0;mi<2;mi++)
          #pragma unroll
          for (int ni=0;ni<4;ni++)
            acc[mi][ni] = __builtin_amdgcn_mfma_f32_16x16x32_bf16(a[mi], bf[ni], acc[mi][ni],0,0,0);
        __builtin_amdgcn_s_setprio(0);
      }
      {
        bf16x8 a[2];
        #pragma unroll
        for (int i=0;i<2;i++) a[i] = *(const bf16x8*)(pA + (2+i)*512);
        if (!lastT) issueB(nb2*2+1, offN + 32);
        __builtin_amdgcn_s_setprio(1);
        #pragma unroll
        for (int mi=0;mi<2;mi++)
          #pragma unroll
          for (int ni=0;ni<4;ni++)
            acc[2+mi][ni] = __builtin_amdgcn_mfma_f32_16x16x32_bf16(a[mi], bf[ni], acc[2+mi][ni],0,0,0);
        __builtin_amdgcn_s_setprio(0);
      }
    }
  }

  const int crow0 = wr*64 + ((lane>>4)<<2);
  const int ccol0 = wc*64 + frow;
  #pragma unroll
  for (int mi=0;mi<4;mi++){
    #pragma unroll
    for (int ni=0;ni<4;ni++){
      long col = n0 + ccol0 + ni*16;
      float bv = (EPI==1) ? bias[col] : 0.0f;
      #pragma unroll
      for (int r=0;r<4;r++){
        long row = m0 + crow0 + mi*16 + r;
        float v = acc[mi][ni][r];
        if (EPI==1){ v += bv; v = v > 0.0f ? v : 0.0f; }
        C[row*(long)ldc + col] = f2bf(v);
      }
    }
  }
}

// ---------------------------------------------------------------------------
// pv5: 128x128 PV GEMM, deep-pipeline schedule, 4 waves, 64KB LDS, 2/CU.
// z -> XCD-pair clustering; 4 bx-blocks sharing a P panel consecutive on one XCD.
__global__ __launch_bounds__(256, 2) void pv5(
    const u16* __restrict__ P0, const u16* __restrict__ P1,
    const u16* __restrict__ P2, const u16* __restrict__ P3,
    const u16* __restrict__ xT, u16* __restrict__ attb)
{
  extern __shared__ u16 pm[];
  const int L = blockIdx.x;
  const int xcd = L & 7;
  const int z = xcd >> 1;
  const int q = L >> 3;
  const int by = ((q >> 2) << 1) + (xcd & 1);
  const int bx = q & 3;
  const long ZS = 4096L*512;
  const u16* A  = (z==0)?P0:(z==1)?P1:(z==2)?P2:P3;
  const u16* Bt = xT   + (long)z*ZS;
  u16*       C  = attb + (long)z*ZS;
  const long m0 = (long)by * 128, n0 = (long)bx * 128;

  const int t = threadIdx.x;
  const int lane = t & 63;
  const int w = t >> 6;
  const int wr = w >> 1, wc = w & 1;

  const int row0 = t >> 2;
  const int cs0  = (t & 3) ^ ((row0 >> 1) & 3);

  const u16* aB0 = A + (m0 + row0)*4096L + cs0*8;
  const u16* aB1 = aB0 + 64*4096L;
  const u16* bB0 = Bt + (n0 + row0)*4096L + cs0*8;
  const u16* bB1 = bB0 + 64*4096L;

  auto issueA = [&](int sub, long off){
    u16* d = pm + sub*4096 + t*8;
    gld16(aB0 + off, d);
    gld16(aB1 + off, d + 2048);
  };
  auto issueB = [&](int sub, long off){
    u16* d = pm + 16384 + sub*4096 + t*8;
    gld16(bB0 + off, d);
    gld16(bB1 + off, d + 2048);
  };

  const int frow = lane & 15;
  const int elemoff = (((lane>>4) ^ ((frow>>1)&3)) << 3);
  const int rAoff = (wr*64 + frow)*32 + elemoff;
  const int rBoff = (wc*64 + frow)*32 + elemoff;

  f32x4 acc[4][4] = {};

  issueA(0, 0);  issueB(0, 0);
  issueA(1, 32); issueB(1, 32);

  const int NT = 64;
  for (int tl = 0; tl < NT; ++tl) {
    const int b = tl & 1;
    const int nb2 = b ^ 1;
    const bool lastT = (tl == NT-1);
    const long offN = (long)(tl+1)*64;

    asm volatile("s_waitcnt vmcnt(4)" ::: "memory");
    __builtin_amdgcn_s_barrier();
    __builtin_amdgcn_sched_barrier(0);

    {
      const u16* pA = pm + (b*2+0)*4096 + rAoff;
      const u16* pB = pm + 16384 + (b*2+0)*4096 + rBoff;
      bf16x8 bf[4];
      #pragma unroll
      for (int i=0;i<4;i++) bf[i] = *(const bf16x8*)(pB + i*512);
      {
        bf16x8 a[2];
        #pragma unroll
        for (int i=0;i<2;i++) a[i] = *(const bf16x8*)(pA + i*512);
        if (!lastT) issueA(nb2*2+0, offN);
        __builtin_amdgcn_s_setprio(1);
        #pragma unroll
        for (int mi=0;mi<2;mi++)
          #pragma unroll
          for (int ni=0;ni<4;ni++)
            acc[mi][ni] = __builtin_amdgcn_mfma_f32_16x16x32_bf16(a[mi], bf[ni], acc[mi][ni],0,0,0);
        __builtin_amdgcn_s_setprio(0);
      }
      {
        bf16x8 a[2];
        #pragma unroll
        for (int i=0;i<2;i++) a[i] = *(const bf16x8*)(pA + (2+i)*512);
        if (!lastT) issueB(nb2*2+0, offN);
        __builtin_amdgcn_s_setprio(1);
        #pragma unroll
        for (int mi=0;mi<2;mi++)
          #pragma unroll
          for (int ni=0;ni<4;ni++)
            acc[2+mi][ni] = __builtin_amdgcn_mfma_f32_16x16x32_bf16(a[mi], bf[ni], acc[2+mi][ni],0,0,0);
        __builtin_amdgcn_s_setprio(0);
      }
    }

    if (lastT) asm volatile("s_waitcnt vmcnt(0)" ::: "memory");
    else       asm volatile("s_waitcnt vmcnt(4)" ::: "memory");
    __builtin_amdgcn_s_barrier();
    __builtin_amdgcn_sched_barrier(0);

    {
      const u16* pA = pm + (b*2+1)*4096 + rAoff;
      const u16* pB = pm + 16384 + (b*2+1)*4096 + rBoff;
      bf16x8 bf[4];
      #pragma unroll
      for (int i=0;i<4;i++) bf[i] = *(const bf16x8*)(pB + i*512);
      {
        bf16x8 a[2];
        #pragma unroll
        for (int i=0;i<2;i++) a[i] = *(const bf16x8*)(pA + i*512);
        if (!lastT) issueA(nb2*2+1, offN + 32);
        __builtin_amdgcn_s_setprio(1);
        #pragma unroll
        for (int mi=0;mi<2;mi++)
          #pragma unroll
          for (int ni=0;ni<4;ni++)
            acc[mi][ni] = __builtin_amdgcn_mfma_f32_16x16x32_bf16(a[mi], bf[ni], acc[mi][ni],0,0,0);
        __builtin_amdgcn_s_setprio(0);
      }
      {
        bf16x8 a[2];
        #pragma unroll
        for (int i=0;i<2;i++) a[i] = *(const bf16x8*)(pA + (2+i)*512);
        if (!lastT) issueB(nb2*2+1, offN + 32);
        __builtin_amdgcn_s_setprio(1);
        #pragma unroll
        for (int mi=0;mi<2;mi++)
          #pragma unroll
          for (int ni=0;ni<4;ni++)
            acc[2+mi][ni] = __builtin_amdgcn_mfma_f32_16x16x32_bf16(a[mi], bf[ni], acc[2+mi][ni],0,0,0);
        __builtin_amdgcn_s_setprio(0);
      }
    }
  }

  const int crow0 = wr*64 + ((lane>>4)<<2);
  const int ccol0 = wc*64 + frow;
  #pragma unroll
  for (int mi=0;mi<4;mi++){
    #pragma unroll
    for (int ni=0;ni<4;ni++){
      long col = n0 + ccol0 + ni*16;
      #pragma unroll
      for (int r=0;r<4;r++){
        long row = m0 + crow0 + mi*16 + r;
        C[row*512 + col] = f2bf(acc[mi][ni][r]);
      }
    }
  }
}

// ---------------------------------------------------------------------------
// Batched in-place row softmax: 4 z-planes. fp16 shifted logits -> bf16 P.
__global__ __launch_bounds__(256) void softmax_batched(
    u16* __restrict__ S0, u16* __restrict__ S1,
    u16* __restrict__ S2, u16* __restrict__ S3)
{
  const int z = blockIdx.x >> 12;
  const long row = blockIdx.x & 4095;
  u16* buf = (z==0)?S0:(z==1)?S1:(z==2)?S2:S3;
  u16* src = buf + row*4096;
  const int t = threadIdx.x, lane = t&63, w = t>>6;
  float v[16];
  #pragma unroll
  for (int i=0;i<2;i++){
    u16x8 q = *(const u16x8*)(src + t*16 + i*8);
    #pragma unroll
    for (int j=0;j<8;j++) v[i*8+j] = h2f(q[j]);
  }
  float mx = v[0];
  #pragma unroll
  for (int i=1;i<16;i++) mx = fmaxf(mx, v[i]);
  #pragma unroll
  for (int off=32; off; off>>=1) mx = fmaxf(mx, __shfl_xor(mx, off));
  __shared__ float red[4];
  if (lane==0) red[w] = mx;
  __syncthreads();
  mx = fmaxf(fmaxf(red[0],red[1]), fmaxf(red[2],red[3]));
  float sum = 0.0f;
  #pragma unroll
  for (int i=0;i<16;i++){ v[i] = __expf(v[i]-mx); sum += v[i]; }
  #pragma unroll
  for (int off=32; off; off>>=1) sum += __shfl_xor(sum, off);
  __shared__ float red2[4];
  if (lane==0) red2[w] = sum;
  __syncthreads();
  sum = red2[0]+red2[1]+red2[2]+red2[3];
  const float inv = 1.0f/sum;
  #pragma unroll
  for (int i=0;i<2;i++){
    u16x8 o;
    #pragma unroll
    for (int j=0;j<8;j++) o[j] = f2bf(v[i*8+j]*inv);
    *(u16x8*)(src + t*16 + i*8) = o;
  }
}

// Row LayerNorm over 512 (optional residual add), bf16 out
template<int ADD>
__global__ __launch_bounds__(256) void ln_row(
    const u16* __restrict__ X, const u16* __restrict__ Y,
    const float* __restrict__ w, const float* __restrict__ b,
    u16* __restrict__ outB)
{
  const long row = blockIdx.x;
  const int t = threadIdx.x, lane = t&63, wv = t>>6;
  ushort2 xv = *(const ushort2*)(X + row*512 + t*2);
  float v0 = bf2f(xv.x), v1 = bf2f(xv.y);
  if (ADD){
    ushort2 yv = *(const ushort2*)(Y + row*512 + t*2);
    v0 += bf2f(yv.x); v1 += bf2f(yv.y);
  }
  float s = v0+v1, q = v0*v0 + v1*v1;
  #pragma unroll
  for (int off=32; off; off>>=1){ s += __shfl_xor(s,off); q += __shfl_xor(q,off); }
  __shared__ float red[8];
  if (lane==0){ red[wv]=s; red[4+wv]=q; }
  __syncthreads();
  s = red[0]+red[1]+red[2]+red[3];
  q = red[4]+red[5]+red[6]+red[7];
  const float u = s*(1.0f/512.0f);
  const float var = q*(1.0f/512.0f) - u*u;
  const float inv = rsqrtf(var + 1e-12f);
  const int c = t*2;
  float o0 = (v0-u)*inv*w[c]   + b[c];
  float o1 = (v1-u)*inv*w[c+1] + b[c+1];
  ushort2 ov; ov.x=f2bf(o0); ov.y=f2bf(o1);
  *(ushort2*)(outB + row*512 + c) = ov;
}

// ---------------------------------------------------------------------------
extern "C" void kernel_launch(void* const* d_in, const int* in_sizes, int n_in,
                              void* d_out, int out_size, void* d_ws, size_t ws_size,
                              hipStream_t stream) {
  const float* T1   = (const float*)d_in[0];
  const float* T2   = (const float*)d_in[1];
  const float* w3   = (const float*)d_in[2];
  const float* w1   = (const float*)d_in[3];
  const float* bg   = (const float*)d_in[4];
  const float* bb   = (const float*)d_in[5];
  const float* bm   = (const float*)d_in[6];
  const float* bv   = (const float*)d_in[7];
  const float* ln1w = (const float*)d_in[8];
  const float* ln1b = (const float*)d_in[9];
  const float* linw = (const float*)d_in[10];
  const float* linb = (const float*)d_in[11];
  const float* ln2w = (const float*)d_in[12];
  const float* ln2b = (const float*)d_in[13];

  hipFuncSetAttribute(reinterpret_cast<const void*>(gemm256<0,1>),
                      hipFuncAttributeMaxDynamicSharedMemorySize, 131072);
  hipFuncSetAttribute(reinterpret_cast<const void*>(gemm256<3,0>),
                      hipFuncAttributeMaxDynamicSharedMemorySize, 131072);
  hipFuncSetAttribute(reinterpret_cast<const void*>(pv5),
                      hipFuncAttributeMaxDynamicSharedMemorySize, 65536);
  hipFuncSetAttribute(reinterpret_cast<const void*>(gemm128_deep<0>),
                      hipFuncAttributeMaxDynamicSharedMemorySize, 65536);
  hipFuncSetAttribute(reinterpret_cast<const void*>(gemm128_deep<1>),
                      hipFuncAttributeMaxDynamicSharedMemorySize, 65536);

  char* ws = (char*)d_ws;
  size_t off = 0;
  auto alloc = [&](size_t bytes)->char* {
    char* p = ws + off;
    off += (bytes + 255) & ~(size_t)255;
    return p;
  };
  const size_t XPAD_B = 4L*66*66*1024*2;
  u16*   Xpad  = (u16*)  alloc(XPAD_B);               // aliased as S3 after conv3
  u16*   wk3t  = (u16*)  alloc(1024L*9216*2);
  u16*   w1t   = (u16*)  alloc(512L*1024*2);
  u16*   lint  = (u16*)  alloc(512L*512*2);
  float* bias1 = (float*)alloc(512*4);
  float* nrm   = (float*)alloc(16384L*4);
  u16*   Y1    = (u16*)  alloc(16384L*1024*2);        // aliased as S0 after conv1
  u16*   x0    = (u16*)  alloc(16384L*512*2);         // reused as final bf16 buf
  u16*   xT    = (u16*)  alloc(4L*512*4096*2);
  u16*   Sreg  = (u16*)  alloc(2L*4096*4096*2);       // S1 (lower) + S2 (upper)
  u16*   attb  = (u16*)  alloc(16384L*512*2);
  u16*   h     = (u16*)  alloc(16384L*512*2);
  u16*   g     = (u16*)  alloc(16384L*512*2);
  u16*   rel1  = (u16*)  alloc(16384L*512*2);
  u16*   S0    = Y1;
  u16*   S1    = Sreg;
  u16*   S2    = Sreg + 4096L*4096;
  u16*   S3    = Xpad;
  if (off > ws_size) return;  // workspace too small -> visible failure

  const long ZS = 4096L*512;

  // --- prep ---
  border_zero<<<dim3(260,4), 256, 0, stream>>>(Xpad);
  pad_interior<<<dim3(64,16,4), 256, 0, stream>>>(T1, T2, Xpad);
  prep_w3<<<1024, 256, 0, stream>>>(w3, wk3t);
  prep_small<<<3074, 256, 0, stream>>>(w1, bg, bb, bm, bv, linw, w1t, lint, bias1);

  // --- conv3x3 -> Y1 ; conv1x1+BN+ReLU -> x0 ---
  gemm256<0,1><<<dim3(4,64), 512, 131072, stream>>>(Xpad, wk3t, (void*)Y1, 9216, 0, 9216, 1024,
                                                    nullptr, nullptr, nullptr, nullptr, nullptr);
  gemm128_deep<1><<<512, 256, 65536, stream>>>(Y1, w1t, x0, bias1, 1024, 1024, 1024, 512);

  // --- attention: symmetric batched S-GEMM, batched in-place softmax, pv5 ---
  auto attend = [&](const u16* xin){
    transpose_bf<<<dim3(64,8,4), 256, 0, stream>>>(xin, xT, 4096, 512, ZS, ZS);
    row_norm<<<4096, 256, 0, stream>>>(xin, nrm);
    gemm256<3,0><<<dim3(544), 512, 131072, stream>>>(xin, xin, nullptr, 512, 512, 512, 4096,
                                                     nrm, S0, S1, S2, S3);
    softmax_batched<<<16384, 256, 0, stream>>>(S0, S1, S2, S3);
    pv5<<<512, 256, 65536, stream>>>(S0, S1, S2, S3, xT, attb);
  };

  // --- block 1 ---
  attend(x0);
  ln_row<1><<<16384, 256, 0, stream>>>(x0, attb, ln1w, ln1b, h);
  gemm128_deep<1><<<512, 256, 65536, stream>>>(h, lint, g, linb, 512, 512, 512, 512);
  ln_row<0><<<16384, 256, 0, stream>>>(g, nullptr, ln2w, ln2b, rel1);

  // --- block 2 (same params) ---
  attend(rel1);
  ln_row<1><<<16384, 256, 0, stream>>>(rel1, attb, ln1w, ln1b, h);
  gemm128_deep<1><<<512, 256, 65536, stream>>>(h, lint, g, linb, 512, 512, 512, 512);
  ln_row<0><<<16384, 256, 0, stream>>>(g, nullptr, ln2w, ln2b, x0);

  // --- final NHWC bf16 -> NCHW f32 ---
  transpose_bf_f32<<<dim3(64,8,4), 256, 0, stream>>>(x0, (float*)d_out);
}

// Round 14
// 784.302 us; speedup vs baseline: 1.0527x; 1.0135x over previous
//
#include <hip/hip_runtime.h>
#include <stdint.h>

typedef float f32x4 __attribute__((ext_vector_type(4)));
typedef __bf16 bf16x8 __attribute__((ext_vector_type(8)));
typedef unsigned short u16;
typedef unsigned short u16x8 __attribute__((ext_vector_type(8)));

__device__ __forceinline__ float bf2f(u16 u){ unsigned int i = ((unsigned int)u)<<16; float f; __builtin_memcpy(&f,&i,4); return f; }
__device__ __forceinline__ u16 f2bf(float f){ unsigned int i; __builtin_memcpy(&i,&f,4); i += 0x7FFFu + ((i>>16)&1u); return (u16)(i>>16); }
__device__ __forceinline__ u16 f2h(float f){ _Float16 h = (_Float16)f; u16 b; __builtin_memcpy(&b,&h,2); return b; }
__device__ __forceinline__ float h2f(u16 b){ _Float16 h; __builtin_memcpy(&h,&b,2); return (float)h; }

__device__ __forceinline__ void gld16(const void* g, void* l){
  __builtin_amdgcn_global_load_lds(
      (const __attribute__((address_space(1))) void*)(uintptr_t)g,
      (__attribute__((address_space(3))) void*)(unsigned int)(uintptr_t)l, 16, 0, 0);
}

// ---------------------------------------------------------------------------
// Zero only the border pixels of Xpad [4][66][66][1024].
__global__ __launch_bounds__(256) void border_zero(u16* __restrict__ Xpad){
  const int n = blockIdx.y, p = blockIdx.x;   // p in 0..259
  int y, x;
  if (p < 66)        { y = 0;        x = p; }
  else if (p < 132)  { y = 65;       x = p - 66; }
  else if (p < 196)  { y = p - 131;  x = 0; }
  else               { y = p - 195;  x = 65; }
  ushort4 z = {0,0,0,0};
  *(ushort4*)(Xpad + (((long)n*66 + y)*66 + x)*1024 + threadIdx.x*4) = z;
}

// Prep: concat(T1,T2) NCHW f32 -> Xpad interior bf16.
__global__ __launch_bounds__(256) void pad_interior(const float* __restrict__ T1,
                                                    const float* __restrict__ T2,
                                                    u16* __restrict__ Xpad){
  const int n = blockIdx.z, ct = blockIdx.y, pt = blockIdx.x;
  const int t = threadIdx.x;
  const int c0 = ct*64, p0 = pt*64;
  const float* src = (c0 < 512) ? (T1 + ((long)n*512 + c0)*4096)
                                : (T2 + ((long)n*512 + (c0-512))*4096);
  __shared__ u16 lds[64][66];
  #pragma unroll
  for (int i=0;i<4;i++){
    int c = i*16 + (t>>4);
    int ch = t&15;
    float4 v = *(const float4*)(src + (long)c*4096 + p0 + ch*4);
    int p = ch*4;
    lds[p+0][c] = f2bf(v.x); lds[p+1][c] = f2bf(v.y);
    lds[p+2][c] = f2bf(v.z); lds[p+3][c] = f2bf(v.w);
  }
  __syncthreads();
  #pragma unroll
  for (int i=0;i<8;i++){
    int p = i*8 + (t>>5);
    int c2 = t&31;
    int pix = p0 + p; int yy = (pix>>6)+1, xx = (pix&63)+1;
    ushort2 val; val.x = lds[p][2*c2]; val.y = lds[p][2*c2+1];
    *(ushort2*)(Xpad + (((long)n*66 + yy)*66 + xx)*1024 + c0 + 2*c2) = val;
  }
}

// w_conv3 [o][ci][3][3] f32 -> wk3t [o][tap][ci] bf16
__global__ __launch_bounds__(256) void prep_w3(const float* __restrict__ w3, u16* __restrict__ wk3t){
  const int o = blockIdx.x; const int t = threadIdx.x;
  __shared__ u16 lds[9216];
  const float* src = w3 + (long)o*9216;
  #pragma unroll
  for (int i=0;i<9;i++){
    int j = i*256 + t;
    float4 v = *(const float4*)(src + j*4);
    lds[j*4+0]=f2bf(v.x); lds[j*4+1]=f2bf(v.y); lds[j*4+2]=f2bf(v.z); lds[j*4+3]=f2bf(v.w);
  }
  __syncthreads();
  u16* dst = wk3t + (long)o*9216;
  #pragma unroll
  for (int i=0;i<36;i++){
    int j = i*256 + t; int tp = j>>10, ci = j&1023;
    dst[j] = lds[ci*9+tp];
  }
}

// merged small prep: w1t (2048 blocks), lint (1024 blocks), bias1 (2 blocks)
__global__ void prep_small(const float* __restrict__ w1, const float* __restrict__ bg,
                           const float* __restrict__ bb, const float* __restrict__ bm,
                           const float* __restrict__ bv, const float* __restrict__ linw,
                           u16* __restrict__ w1t, u16* __restrict__ lint,
                           float* __restrict__ bias1){
  const int b = blockIdx.x, t = threadIdx.x;
  if (b < 2048){
    long i = (long)b*256 + t;
    int o = (int)(i>>10);
    float inv = bg[o] / sqrtf(bv[o] + 1e-5f);
    w1t[i] = f2bf(w1[i]*inv);
  } else if (b < 3072){
    long i = (long)(b-2048)*256 + t;
    lint[i] = f2bf(linw[i]);
  } else {
    int o = (b-3072)*256 + t;
    float inv = bg[o]/sqrtf(bv[o]+1e-5f);
    bias1[o] = bb[o] - bm[o]*inv;
  }
}

// per-row squared norm of bf16 [rows][512] -> f32 (softmax shift reference)
__global__ __launch_bounds__(256) void row_norm(const u16* __restrict__ x, float* __restrict__ nrm){
  const int row = blockIdx.x*4 + (threadIdx.x>>6);
  const int lane = threadIdx.x & 63;
  u16x8 q = *(const u16x8*)(x + (long)row*512 + lane*8);
  float s = 0.f;
  #pragma unroll
  for (int j=0;j<8;j++){ float f = bf2f(q[j]); s += f*f; }
  #pragma unroll
  for (int off=32; off; off>>=1) s += __shfl_xor(s, off);
  if (lane==0) nrm[row] = s;
}

// bf16 transpose: dst[c][r] = src[r][c], tiles 64x64
__global__ __launch_bounds__(256) void transpose_bf(const u16* __restrict__ src, u16* __restrict__ dst,
                                                    int R, int C, long sStr, long dStr){
  const int z = blockIdx.z;
  src += (long)z*sStr; dst += (long)z*dStr;
  const int r0 = blockIdx.x*64, c0 = blockIdx.y*64;
  const int t = threadIdx.x;
  __shared__ u16 lds[64][66];
  #pragma unroll
  for (int i=0;i<4;i++){
    int r = i*16 + (t>>4), ch = t&15;
    ushort4 v = *(const ushort4*)(src + (long)(r0+r)*C + c0 + ch*4);
    lds[r][ch*4+0]=v.x; lds[r][ch*4+1]=v.y; lds[r][ch*4+2]=v.z; lds[r][ch*4+3]=v.w;
  }
  __syncthreads();
  #pragma unroll
  for (int i=0;i<4;i++){
    int c = i*16 + (t>>4), ch = t&15;
    ushort4 v;
    v.x = lds[ch*4+0][c]; v.y = lds[ch*4+1][c]; v.z = lds[ch*4+2][c]; v.w = lds[ch*4+3][c];
    *(ushort4*)(dst + (long)(c0+c)*R + r0 + ch*4) = v;
  }
}

// bf16 [4096][512] -> f32 NCHW [512][4096] transpose (final output)
__global__ __launch_bounds__(256) void transpose_bf_f32(const u16* __restrict__ src, float* __restrict__ dst){
  const int z = blockIdx.z;
  src += (long)z*4096*512; dst += (long)z*512*4096;
  const int r0 = blockIdx.x*64, c0 = blockIdx.y*64;
  const int t = threadIdx.x;
  __shared__ u16 lds[64][66];
  #pragma unroll
  for (int i=0;i<4;i++){
    int r = i*16 + (t>>4), ch = t&15;
    ushort4 v = *(const ushort4*)(src + (long)(r0+r)*512 + c0 + ch*4);
    lds[r][ch*4+0]=v.x; lds[r][ch*4+1]=v.y; lds[r][ch*4+2]=v.z; lds[r][ch*4+3]=v.w;
  }
  __syncthreads();
  #pragma unroll
  for (int i=0;i<4;i++){
    int c = i*16 + (t>>4), ch = t&15;
    float4 v;
    v.x = bf2f(lds[ch*4+0][c]); v.y = bf2f(lds[ch*4+1][c]);
    v.z = bf2f(lds[ch*4+2][c]); v.w = bf2f(lds[ch*4+3][c]);
    *(float4*)(dst + (long)(c0+c)*4096 + r0 + ch*4) = v;
  }
}

// ---------------------------------------------------------------------------
// 256x256 deep-pipelined bf16 MFMA GEMM (conv3 only), BK=64, 8 waves.
// Two-wait interleaved schedule, counted vmcnt(4), XCD swizzle.
template<int EPI, int CONV>
__global__ __launch_bounds__(512, 2) void gemm256(
    const u16* __restrict__ Ain, const u16* __restrict__ Btin, void* __restrict__ Cv,
    int K, int lda, int ldb, int ldc)
{
  extern __shared__ u16 sm[];
  const int t = threadIdx.x;
  const int lane = t & 63;
  const int wid = t >> 6;
  const int wr = wid >> 2, wc = wid & 3;

  const int orig = blockIdx.y * gridDim.x + blockIdx.x;
  const int cpx = (gridDim.x * gridDim.y) >> 3;
  const int swz = (orig & 7) * cpx + (orig >> 3);
  const int bx = swz % gridDim.x;
  const int by = swz / gridDim.x;
  const long m0 = (long)by * 256, n0 = (long)bx * 256;
  const u16* A = Ain; const u16* Bt = Btin; u16* Cz = (u16*)Cv;

  const int row0 = t >> 2;
  const int cs0  = (t & 3) ^ ((row0 >> 1) & 3);

  const u16 *aB0, *aB1;
  if (CONV) {
    long m_ = m0 + row0;
    long pb0 = ((long)((int)(m_>>12)*66 + (int)((m_>>6)&63)))*66 + (int)(m_&63);
    m_ = m0 + row0 + 128;
    long pb1 = ((long)((int)(m_>>12)*66 + (int)((m_>>6)&63)))*66 + (int)(m_&63);
    aB0 = A + pb0*1024 + cs0*8;
    aB1 = A + pb1*1024 + cs0*8;
  } else {
    aB0 = A + (m0 + row0)*(long)lda + cs0*8;
    aB1 = A + (m0 + row0 + 128)*(long)lda + cs0*8;
  }
  const u16* bB0 = Bt + (n0 + row0)*(long)ldb + cs0*8;
  const u16* bB1 = Bt + (n0 + row0 + 128)*(long)ldb + cs0*8;

  auto issueA = [&](int sub, long aoff){
    u16* d = sm + sub*8192 + t*8;
    gld16(aB0 + aoff, d);
    gld16(aB1 + aoff, d + 4096);
  };
  auto issueB = [&](int sub, long boff){
    u16* d = sm + 32768 + sub*8192 + t*8;
    gld16(bB0 + boff, d);
    gld16(bB1 + boff, d + 4096);
  };
  auto conv_aoff = [&](int tile)->long {
    int kb = tile << 6;
    int tap = kb >> 10;
    int cb  = kb & 1023;
    int ky = (tap >= 6) ? 2 : (tap >= 3 ? 1 : 0);
    int kx = tap - ky*3;
    return (long)(ky*66 + kx)*1024 + cb;
  };

  const int frow = lane & 15;
  const int elemoff = (((lane>>4) ^ ((frow>>1)&3)) << 3);
  const int rAoff = (wr*128 + frow)*32 + elemoff;
  const int rBoff = (wc*64  + frow)*32 + elemoff;

  f32x4 acc[8][4] = {};

  {
    long a0 = CONV ? conv_aoff(0) : 0L;
    issueA(0, a0);
    issueB(0, 0);
    issueA(1, a0 + 32);
    issueB(1, 32);
  }

  const int NT = K >> 6;
  for (int tile = 0; tile < NT; ++tile) {
    const int b = tile & 1;
    const int nb2 = b ^ 1;
    const bool lastT = (tile == NT-1);
    long aoffN = 0, boffN = 0;
    if (!lastT) {
      aoffN = CONV ? conv_aoff(tile+1) : (long)(tile+1)*64;
      boffN = (long)(tile+1)*64;
    }

    asm volatile("s_waitcnt vmcnt(4)" ::: "memory");
    __builtin_amdgcn_s_barrier();
    __builtin_amdgcn_sched_barrier(0);

    {
      const u16* pA = sm + (b*2+0)*8192 + rAoff;
      const u16* pB = sm + 32768 + (b*2+0)*8192 + rBoff;
      bf16x8 bf[4];
      #pragma unroll
      for (int i=0;i<4;i++) bf[i] = *(const bf16x8*)(pB + i*512);
      {
        bf16x8 a[4];
        #pragma unroll
        for (int i=0;i<4;i++) a[i] = *(const bf16x8*)(pA + i*512);
        if (!lastT) issueA(nb2*2+0, aoffN);
        __builtin_amdgcn_s_setprio(1);
        #pragma unroll
        for (int mi=0;mi<4;mi++)
          #pragma unroll
          for (int ni=0;ni<4;ni++)
            acc[mi][ni] = __builtin_amdgcn_mfma_f32_16x16x32_bf16(a[mi], bf[ni], acc[mi][ni],0,0,0);
        __builtin_amdgcn_s_setprio(0);
      }
      {
        bf16x8 a[4];
        #pragma unroll
        for (int i=0;i<4;i++) a[i] = *(const bf16x8*)(pA + (4+i)*512);
        if (!lastT) issueB(nb2*2+0, boffN);
        __builtin_amdgcn_s_setprio(1);
        #pragma unroll
        for (int mi=0;mi<4;mi++)
          #pragma unroll
          for (int ni=0;ni<4;ni++)
            acc[4+mi][ni] = __builtin_amdgcn_mfma_f32_16x16x32_bf16(a[mi], bf[ni], acc[4+mi][ni],0,0,0);
        __builtin_amdgcn_s_setprio(0);
      }
    }

    if (lastT) asm volatile("s_waitcnt vmcnt(0)" ::: "memory");
    else       asm volatile("s_waitcnt vmcnt(4)" ::: "memory");
    __builtin_amdgcn_s_barrier();
    __builtin_amdgcn_sched_barrier(0);

    {
      const u16* pA = sm + (b*2+1)*8192 + rAoff;
      const u16* pB = sm + 32768 + (b*2+1)*8192 + rBoff;
      bf16x8 bf[4];
      #pragma unroll
      for (int i=0;i<4;i++) bf[i] = *(const bf16x8*)(pB + i*512);
      {
        bf16x8 a[4];
        #pragma unroll
        for (int i=0;i<4;i++) a[i] = *(const bf16x8*)(pA + i*512);
        if (!lastT) issueA(nb2*2+1, aoffN + 32);
        __builtin_amdgcn_s_setprio(1);
        #pragma unroll
        for (int mi=0;mi<4;mi++)
          #pragma unroll
          for (int ni=0;ni<4;ni++)
            acc[mi][ni] = __builtin_amdgcn_mfma_f32_16x16x32_bf16(a[mi], bf[ni], acc[mi][ni],0,0,0);
        __builtin_amdgcn_s_setprio(0);
      }
      {
        bf16x8 a[4];
        #pragma unroll
        for (int i=0;i<4;i++) a[i] = *(const bf16x8*)(pA + (4+i)*512);
        if (!lastT) issueB(nb2*2+1, boffN + 32);
        __builtin_amdgcn_s_setprio(1);
        #pragma unroll
        for (int mi=0;mi<4;mi++)
          #pragma unroll
          for (int ni=0;ni<4;ni++)
            acc[4+mi][ni] = __builtin_amdgcn_mfma_f32_16x16x32_bf16(a[mi], bf[ni], acc[4+mi][ni],0,0,0);
        __builtin_amdgcn_s_setprio(0);
      }
    }
  }

  const int crow0 = wr*128 + ((lane>>4)<<2);
  const int ccol0 = wc*64 + frow;
  #pragma unroll
  for (int mi=0;mi<8;mi++){
    #pragma unroll
    for (int ni=0;ni<4;ni++){
      long col = n0 + ccol0 + ni*16;
      #pragma unroll
      for (int r=0;r<4;r++){
        long row = m0 + crow0 + mi*16 + r;
        Cz[row*(long)ldc + col] = f2bf(acc[mi][ni][r]);
      }
    }
  }
}

// ---------------------------------------------------------------------------
// s_gemm128: SYMMETRIC batched S = x.x^T on the proven gemm128_deep shape:
// 128^2 tile, BK=64, 256 thr/4 waves, 64KB LDS, 2 blocks/CU, two-wait
// interleaved schedule. 2112 blocks = 4z x 528 upper-tri 128^2 tiles (by<=bx),
// z -> XCD pair. Stores fp16(v - srow[row]); off-diag also writes the
// transposed tile (bit-identical by MFMA operand commutativity) via LDS reuse.
__global__ __launch_bounds__(256, 2) void s_gemm128(
    const u16* __restrict__ xin, const float* __restrict__ srowIn,
    u16* __restrict__ C0, u16* __restrict__ C1, u16* __restrict__ C2, u16* __restrict__ C3)
{
  extern __shared__ u16 pm[];
  const int L = blockIdx.x;                 // 0..2111
  const int xcd = L & 7;
  const int z = xcd >> 1;
  const int tid = (xcd & 1)*264 + (L >> 3); // 0..527 within z
  int p = tid, by = 0;
  while (p >= 32 - by){ p -= 32 - by; by++; }
  const int bx = by + p;                    // by <= bx
  const long m0 = (long)by * 128, n0 = (long)bx * 128;

  const u16* A = xin + (long)z*4096*512;
  const float* srow = srowIn + (long)z*4096;
  u16* Cz = (z==0)?C0:(z==1)?C1:(z==2)?C2:C3;
  const int ldc = 4096;

  const int t = threadIdx.x;
  const int lane = t & 63;
  const int w = t >> 6;
  const int wr = w >> 1, wc = w & 1;

  const int row0 = t >> 2;                  // 0..63
  const int cs0  = (t & 3) ^ ((row0 >> 1) & 3);

  const u16* aB0 = A + (m0 + row0)*512L + cs0*8;
  const u16* aB1 = aB0 + 64*512L;
  const u16* bB0 = A + (n0 + row0)*512L + cs0*8;
  const u16* bB1 = bB0 + 64*512L;

  auto issueA = [&](int sub, long off){
    u16* d = pm + sub*4096 + t*8;
    gld16(aB0 + off, d);
    gld16(aB1 + off, d + 2048);
  };
  auto issueB = [&](int sub, long off){
    u16* d = pm + 16384 + sub*4096 + t*8;
    gld16(bB0 + off, d);
    gld16(bB1 + off, d + 2048);
  };

  const int frow = lane & 15;
  const int elemoff = (((lane>>4) ^ ((frow>>1)&3)) << 3);
  const int rAoff = (wr*64 + frow)*32 + elemoff;
  const int rBoff = (wc*64 + frow)*32 + elemoff;

  f32x4 acc[4][4] = {};

  issueA(0, 0);  issueB(0, 0);
  issueA(1, 32); issueB(1, 32);

  const int NT = 8;                         // K=512 / 64
  for (int tl = 0; tl < NT; ++tl) {
    const int b = tl & 1;
    const int nb2 = b ^ 1;
    const bool lastT = (tl == NT-1);
    const long offN = (long)(tl+1)*64;

    asm volatile("s_waitcnt vmcnt(4)" ::: "memory");
    __builtin_amdgcn_s_barrier();
    __builtin_amdgcn_sched_barrier(0);

    {
      const u16* pA = pm + (b*2+0)*4096 + rAoff;
      const u16* pB = pm + 16384 + (b*2+0)*4096 + rBoff;
      bf16x8 bf[4];
      #pragma unroll
      for (int i=0;i<4;i++) bf[i] = *(const bf16x8*)(pB + i*512);
      {
        bf16x8 a[2];
        #pragma unroll
        for (int i=0;i<2;i++) a[i] = *(const bf16x8*)(pA + i*512);
        if (!lastT) issueA(nb2*2+0, offN);
        __builtin_amdgcn_s_setprio(1);
        #pragma unroll
        for (int mi=0;mi<2;mi++)
          #pragma unroll
          for (int ni=0;ni<4;ni++)
            acc[mi][ni] = __builtin_amdgcn_mfma_f32_16x16x32_bf16(a[mi], bf[ni], acc[mi][ni],0,0,0);
        __builtin_amdgcn_s_setprio(0);
      }
      {
        bf16x8 a[2];
        #pragma unroll
        for (int i=0;i<2;i++) a[i] = *(const bf16x8*)(pA + (2+i)*512);
        if (!lastT) issueB(nb2*2+0, offN);
        __builtin_amdgcn_s_setprio(1);
        #pragma unroll
        for (int mi=0;mi<2;mi++)
          #pragma unroll
          for (int ni=0;ni<4;ni++)
            acc[2+mi][ni] = __builtin_amdgcn_mfma_f32_16x16x32_bf16(a[mi], bf[ni], acc[2+mi][ni],0,0,0);
        __builtin_amdgcn_s_setprio(0);
      }
    }

    if (lastT) asm volatile("s_waitcnt vmcnt(0)" ::: "memory");
    else       asm volatile("s_waitcnt vmcnt(4)" ::: "memory");
    __builtin_amdgcn_s_barrier();
    __builtin_amdgcn_sched_barrier(0);

    {
      const u16* pA = pm + (b*2+1)*4096 + rAoff;
      const u16* pB = pm + 16384 + (b*2+1)*4096 + rBoff;
      bf16x8 bf[4];
      #pragma unroll
      for (int i=0;i<4;i++) bf[i] = *(const bf16x8*)(pB + i*512);
      {
        bf16x8 a[2];
        #pragma unroll
        for (int i=0;i<2;i++) a[i] = *(const bf16x8*)(pA + i*512);
        if (!lastT) issueA(nb2*2+1, offN + 32);
        __builtin_amdgcn_s_setprio(1);
        #pragma unroll
        for (int mi=0;mi<2;mi++)
          #pragma unroll
          for (int ni=0;ni<4;ni++)
            acc[mi][ni] = __builtin_amdgcn_mfma_f32_16x16x32_bf16(a[mi], bf[ni], acc[mi][ni],0,0,0);
        __builtin_amdgcn_s_setprio(0);
      }
      {
        bf16x8 a[2];
        #pragma unroll
        for (int i=0;i<2;i++) a[i] = *(const bf16x8*)(pA + (2+i)*512);
        if (!lastT) issueB(nb2*2+1, offN + 32);
        __builtin_amdgcn_s_setprio(1);
        #pragma unroll
        for (int mi=0;mi<2;mi++)
          #pragma unroll
          for (int ni=0;ni<4;ni++)
            acc[2+mi][ni] = __builtin_amdgcn_mfma_f32_16x16x32_bf16(a[mi], bf[ni], acc[2+mi][ni],0,0,0);
        __builtin_amdgcn_s_setprio(0);
      }
    }
  }

  const int crow0 = wr*64 + ((lane>>4)<<2);
  const int ccol0 = wc*64 + frow;

  // normal store: fp16(v - srow[row])
  #pragma unroll
  for (int mi=0;mi<4;mi++){
    #pragma unroll
    for (int r=0;r<4;r++){
      long row = m0 + crow0 + mi*16 + r;
      float sr = srow[row];
      u16* cb = Cz + row*(long)ldc + n0 + ccol0;
      #pragma unroll
      for (int ni=0;ni<4;ni++)
        cb[ni*16] = f2h(acc[mi][ni][r] - sr);
    }
  }

  // off-diagonal: transposed tile via LDS reuse (bit-identical values)
  if (bx != by){
    __syncthreads();                 // staging LDS dead for all waves
    u16* lt = pm;                    // 128x128 fp16: [col_l][32 units of 4 rows]
    float sc[4];
    #pragma unroll
    for (int ni=0;ni<4;ni++) sc[ni] = srow[n0 + ccol0 + ni*16];
    #pragma unroll
    for (int mi=0;mi<4;mi++){
      const int g = (crow0 + mi*16) >> 2;        // unit 0..31
      #pragma unroll
      for (int ni=0;ni<4;ni++){
        const int col_l = ccol0 + ni*16;
        ushort4 pk;
        #pragma unroll
        for (int r=0;r<4;r++) pk[r] = f2h(acc[mi][ni][r] - sc[ni]);
        *(ushort4*)(lt + col_l*128 + ((g ^ (col_l & 31))<<2)) = pk;
      }
    }
    __syncthreads();
    const int half = lane >> 5, l32 = lane & 31;
    #pragma unroll
    for (int ps=0; ps<16; ps++){
      const int R = ps*8 + w*2 + half;           // S^T row (= orig col), 0..127
      const int u = l32 ^ (R & 31);
      ushort4 a = *(const ushort4*)(lt + R*128 + (u<<2));
      *(ushort4*)(Cz + (n0 + R)*(long)ldc + m0 + (l32<<2)) = a;
    }
  }
}

// ---------------------------------------------------------------------------
// gemm128_deep: generic 128x128 BK=64 deep-pipelined GEMM, 2 blocks/CU,
// bx-grouped XCD mapping. EPI: 0 = bf16 store, 1 = bf16 + bias + relu.
template<int EPI>
__global__ __launch_bounds__(256, 2) void gemm128_deep(
    const u16* __restrict__ A, const u16* __restrict__ Bt, u16* __restrict__ C,
    const float* __restrict__ bias, int K, int lda, int ldb, int ldc)
{
  extern __shared__ u16 pm[];
  const int L = blockIdx.x;
  const int xcd = L & 7;
  const int q = L >> 3;
  const int by = (q >> 2) + xcd*16;
  const int bx = q & 3;
  const long m0 = (long)by * 128, n0 = (long)bx * 128;

  const int t = threadIdx.x;
  const int lane = t & 63;
  const int w = t >> 6;
  const int wr = w >> 1, wc = w & 1;

  const int row0 = t >> 2;
  const int cs0  = (t & 3) ^ ((row0 >> 1) & 3);

  const u16* aB0 = A + (m0 + row0)*(long)lda + cs0*8;
  const u16* aB1 = aB0 + 64*(long)lda;
  const u16* bB0 = Bt + (n0 + row0)*(long)ldb + cs0*8;
  const u16* bB1 = bB0 + 64*(long)ldb;

  auto issueA = [&](int sub, long off){
    u16* d = pm + sub*4096 + t*8;
    gld16(aB0 + off, d);
    gld16(aB1 + off, d + 2048);
  };
  auto issueB = [&](int sub, long off){
    u16* d = pm + 16384 + sub*4096 + t*8;
    gld16(bB0 + off, d);
    gld16(bB1 + off, d + 2048);
  };

  const int frow = lane & 15;
  const int elemoff = (((lane>>4) ^ ((frow>>1)&3)) << 3);
  const int rAoff = (wr*64 + frow)*32 + elemoff;
  const int rBoff = (wc*64 + frow)*32 + elemoff;

  f32x4 acc[4][4] = {};

  issueA(0, 0);  issueB(0, 0);
  issueA(1, 32); issueB(1, 32);

  const int NT = K >> 6;
  for (int tl = 0; tl < NT; ++tl) {
    const int b = tl & 1;
    const int nb2 = b ^ 1;
    const bool lastT = (tl == NT-1);
    const long offN = (long)(tl+1)*64;

    asm volatile("s_waitcnt vmcnt(4)" ::: "memory");
    __builtin_amdgcn_s_barrier();
    __builtin_amdgcn_sched_barrier(0);

    {
      const u16* pA = pm + (b*2+0)*4096 + rAoff;
      const u16* pB = pm + 16384 + (b*2+0)*4096 + rBoff;
      bf16x8 bf[4];
      #pragma unroll
      for (int i=0;i<4;i++) bf[i] = *(const bf16x8*)(pB + i*512);
      {
        bf16x8 a[2];
        #pragma unroll
        for (int i=0;i<2;i++) a[i] = *(const bf16x8*)(pA + i*512);
        if (!lastT) issueA(nb2*2+0, offN);
        __builtin_amdgcn_s_setprio(1);
        #pragma unroll
        for (int mi=0;mi<2;mi++)
          #pragma unroll
          for (int ni=0;ni<4;ni++)
            acc[mi][ni] = __builtin_amdgcn_mfma_f32_16x16x32_bf16(a[mi], bf[ni], acc[mi][ni],0,0,0);
        __builtin_amdgcn_s_setprio(0);
      }
      {
        bf16x8 a[2];
        #pragma unroll
        for (int i=0;i<2;i++) a[i] = *(const bf16x8*)(pA + (2+i)*512);
        if (!lastT) issueB(nb2*2+0, offN);
        __builtin_amdgcn_s_setprio(1);
        #pragma unroll
        for (int mi=0;mi<2;mi++)
          #pragma unroll
          for (int ni=0;ni<4;ni++)
            acc[2+mi][ni] = __builtin_amdgcn_mfma_f32_16x16x32_bf16(a[mi], bf[ni], acc[2+mi][ni],0,0,0);
        __builtin_amdgcn_s_setprio(0);
      }
    }

    if (lastT) asm volatile("s_waitcnt vmcnt(0)" ::: "memory");
    else       asm volatile("s_waitcnt vmcnt(4)" ::: "memory");
    __builtin_amdgcn_s_barrier();
    __builtin_amdgcn_sched_barrier(0);

    {
      const u16* pA = pm + (b*2+1)*4096 + rAoff;
      const u16* pB = pm + 16384 + (b*2+1)*4096 + rBoff;
      bf16x8 bf[4];
      #pragma unroll
      for (int i=0;i<4;i++) bf[i] = *(const bf16x8*)(pB + i*512);
      {
        bf16x8 a[2];
        #pragma unroll
        for (int i=0;i<2;i++) a[i] = *(const bf16x8*)(pA + i*512);
        if (!lastT) issueA(nb2*2+1, offN + 32);
        __builtin_amdgcn_s_setprio(1);
        #pragma unroll
        for (int mi=0;mi<2;mi++)
          #pragma unroll
          for (int ni=0;ni<4;ni++)
            acc[mi][ni] = __builtin_amdgcn_mfma_f32_16x16x32_bf16(a[mi], bf[ni], acc[mi][ni],0,0,0);
        __builtin_amdgcn_s_setprio(0);
      }
      {
        bf16x8 a[2];
        #pragma unroll
        for (int i=0;i<2;i++) a[i] = *(const bf16x8*)(pA + (2+i)*512);
        if (!lastT) issueB(nb2*2+1, offN + 32);
        __builtin_amdgcn_s_setprio(1);
        #pragma unroll
        for (int mi=0;mi<2;mi++)
          #pragma unroll
          for (int ni=0;ni<4;ni++)
            acc[2+mi][ni] = __builtin_amdgcn_mfma_f32_16x16x32_bf16(a[mi], bf[ni], acc[2+mi][ni],0,0,0);
        __builtin_amdgcn_s_setprio(0);
      }
    }
  }

  const int crow0 = wr*64 + ((lane>>4)<<2);
  const int ccol0 = wc*64 + frow;
  #pragma unroll
  for (int mi=0;mi<4;mi++){
    #pragma unroll
    for (int ni=0;ni<4;ni++){
      long col = n0 + ccol0 + ni*16;
      float bv = (EPI==1) ? bias[col] : 0.0f;
      #pragma unroll
      for (int r=0;r<4;r++){
        long row = m0 + crow0 + mi*16 + r;
        float v = acc[mi][ni][r];
        if (EPI==1){ v += bv; v = v > 0.0f ? v : 0.0f; }
        C[row*(long)ldc + col] = f2bf(v);
      }
    }
  }
}

// ---------------------------------------------------------------------------
// pv5: 128x128 PV GEMM, deep-pipeline schedule, 4 waves, 64KB LDS, 2/CU.
// z -> XCD-pair clustering; 4 bx-blocks sharing a P panel consecutive on one XCD.
__global__ __launch_bounds__(256, 2) void pv5(
    const u16* __restrict__ P0, const u16* __restrict__ P1,
    const u16* __restrict__ P2, const u16* __restrict__ P3,
    const u16* __restrict__ xT, u16* __restrict__ attb)
{
  extern __shared__ u16 pm[];
  const int L = blockIdx.x;
  const int xcd = L & 7;
  const int z = xcd >> 1;
  const int q = L >> 3;
  const int by = ((q >> 2) << 1) + (xcd & 1);
  const int bx = q & 3;
  const long ZS = 4096L*512;
  const u16* A  = (z==0)?P0:(z==1)?P1:(z==2)?P2:P3;
  const u16* Bt = xT   + (long)z*ZS;
  u16*       C  = attb + (long)z*ZS;
  const long m0 = (long)by * 128, n0 = (long)bx * 128;

  const int t = threadIdx.x;
  const int lane = t & 63;
  const int w = t >> 6;
  const int wr = w >> 1, wc = w & 1;

  const int row0 = t >> 2;
  const int cs0  = (t & 3) ^ ((row0 >> 1) & 3);

  const u16* aB0 = A + (m0 + row0)*4096L + cs0*8;
  const u16* aB1 = aB0 + 64*4096L;
  const u16* bB0 = Bt + (n0 + row0)*4096L + cs0*8;
  const u16* bB1 = bB0 + 64*4096L;

  auto issueA = [&](int sub, long off){
    u16* d = pm + sub*4096 + t*8;
    gld16(aB0 + off, d);
    gld16(aB1 + off, d + 2048);
  };
  auto issueB = [&](int sub, long off){
    u16* d = pm + 16384 + sub*4096 + t*8;
    gld16(bB0 + off, d);
    gld16(bB1 + off, d + 2048);
  };

  const int frow = lane & 15;
  const int elemoff = (((lane>>4) ^ ((frow>>1)&3)) << 3);
  const int rAoff = (wr*64 + frow)*32 + elemoff;
  const int rBoff = (wc*64 + frow)*32 + elemoff;

  f32x4 acc[4][4] = {};

  issueA(0, 0);  issueB(0, 0);
  issueA(1, 32); issueB(1, 32);

  const int NT = 64;
  for (int tl = 0; tl < NT; ++tl) {
    const int b = tl & 1;
    const int nb2 = b ^ 1;
    const bool lastT = (tl == NT-1);
    const long offN = (long)(tl+1)*64;

    asm volatile("s_waitcnt vmcnt(4)" ::: "memory");
    __builtin_amdgcn_s_barrier();
    __builtin_amdgcn_sched_barrier(0);

    {
      const u16* pA = pm + (b*2+0)*4096 + rAoff;
      const u16* pB = pm + 16384 + (b*2+0)*4096 + rBoff;
      bf16x8 bf[4];
      #pragma unroll
      for (int i=0;i<4;i++) bf[i] = *(const bf16x8*)(pB + i*512);
      {
        bf16x8 a[2];
        #pragma unroll
        for (int i=0;i<2;i++) a[i] = *(const bf16x8*)(pA + i*512);
        if (!lastT) issueA(nb2*2+0, offN);
        __builtin_amdgcn_s_setprio(1);
        #pragma unroll
        for (int mi=0;mi<2;mi++)
          #pragma unroll
          for (int ni=0;ni<4;ni++)
            acc[mi][ni] = __builtin_amdgcn_mfma_f32_16x16x32_bf16(a[mi], bf[ni], acc[mi][ni],0,0,0);
        __builtin_amdgcn_s_setprio(0);
      }
      {
        bf16x8 a[2];
        #pragma unroll
        for (int i=0;i<2;i++) a[i] = *(const bf16x8*)(pA + (2+i)*512);
        if (!lastT) issueB(nb2*2+0, offN);
        __builtin_amdgcn_s_setprio(1);
        #pragma unroll
        for (int mi=0;mi<2;mi++)
          #pragma unroll
          for (int ni=0;ni<4;ni++)
            acc[2+mi][ni] = __builtin_amdgcn_mfma_f32_16x16x32_bf16(a[mi], bf[ni], acc[2+mi][ni],0,0,0);
        __builtin_amdgcn_s_setprio(0);
      }
    }

    if (lastT) asm volatile("s_waitcnt vmcnt(0)" ::: "memory");
    else       asm volatile("s_waitcnt vmcnt(4)" ::: "memory");
    __builtin_amdgcn_s_barrier();
    __builtin_amdgcn_sched_barrier(0);

    {
      const u16* pA = pm + (b*2+1)*4096 + rAoff;
      const u16* pB = pm + 16384 + (b*2+1)*4096 + rBoff;
      bf16x8 bf[4];
      #pragma unroll
      for (int i=0;i<4;i++) bf[i] = *(const bf16x8*)(pB + i*512);
      {
        bf16x8 a[2];
        #pragma unroll
        for (int i=0;i<2;i++) a[i] = *(const bf16x8*)(pA + i*512);
        if (!lastT) issueA(nb2*2+1, offN + 32);
        __builtin_amdgcn_s_setprio(1);
        #pragma unroll
        for (int mi=0;mi<2;mi++)
          #pragma unroll
          for (int ni=0;ni<4;ni++)
            acc[mi][ni] = __builtin_amdgcn_mfma_f32_16x16x32_bf16(a[mi], bf[ni], acc[mi][ni],0,0,0);
        __builtin_amdgcn_s_setprio(0);
      }
      {
        bf16x8 a[2];
        #pragma unroll
        for (int i=0;i<2;i++) a[i] = *(const bf16x8*)(pA + (2+i)*512);
        if (!lastT) issueB(nb2*2+1, offN + 32);
        __builtin_amdgcn_s_setprio(1);
        #pragma unroll
        for (int mi=0;mi<2;mi++)
          #pragma unroll
          for (int ni=0;ni<4;ni++)
            acc[2+mi][ni] = __builtin_amdgcn_mfma_f32_16x16x32_bf16(a[mi], bf[ni], acc[2+mi][ni],0,0,0);
        __builtin_amdgcn_s_setprio(0);
      }
    }
  }

  const int crow0 = wr*64 + ((lane>>4)<<2);
  const int ccol0 = wc*64 + frow;
  #pragma unroll
  for (int mi=0;mi<4;mi++){
    #pragma unroll
    for (int ni=0;ni<4;ni++){
      long col = n0 + ccol0 + ni*16;
      #pragma unroll
      for (int r=0;r<4;r++){
        long row = m0 + crow0 + mi*16 + r;
        C[row*512 + col] = f2bf(acc[mi][ni][r]);
      }
    }
  }
}

// ---------------------------------------------------------------------------
// Batched in-place row softmax: 4 z-planes. fp16 shifted logits -> bf16 P.
__global__ __launch_bounds__(256) void softmax_batched(
    u16* __restrict__ S0, u16* __restrict__ S1,
    u16* __restrict__ S2, u16* __restrict__ S3)
{
  const int z = blockIdx.x >> 12;
  const long row = blockIdx.x & 4095;
  u16* buf = (z==0)?S0:(z==1)?S1:(z==2)?S2:S3;
  u16* src = buf + row*4096;
  const int t = threadIdx.x, lane = t&63, w = t>>6;
  float v[16];
  #pragma unroll
  for (int i=0;i<2;i++){
    u16x8 q = *(const u16x8*)(src + t*16 + i*8);
    #pragma unroll
    for (int j=0;j<8;j++) v[i*8+j] = h2f(q[j]);
  }
  float mx = v[0];
  #pragma unroll
  for (int i=1;i<16;i++) mx = fmaxf(mx, v[i]);
  #pragma unroll
  for (int off=32; off; off>>=1) mx = fmaxf(mx, __shfl_xor(mx, off));
  __shared__ float red[4];
  if (lane==0) red[w] = mx;
  __syncthreads();
  mx = fmaxf(fmaxf(red[0],red[1]), fmaxf(red[2],red[3]));
  float sum = 0.0f;
  #pragma unroll
  for (int i=0;i<16;i++){ v[i] = __expf(v[i]-mx); sum += v[i]; }
  #pragma unroll
  for (int off=32; off; off>>=1) sum += __shfl_xor(sum, off);
  __shared__ float red2[4];
  if (lane==0) red2[w] = sum;
  __syncthreads();
  sum = red2[0]+red2[1]+red2[2]+red2[3];
  const float inv = 1.0f/sum;
  #pragma unroll
  for (int i=0;i<2;i++){
    u16x8 o;
    #pragma unroll
    for (int j=0;j<8;j++) o[j] = f2bf(v[i*8+j]*inv);
    *(u16x8*)(src + t*16 + i*8) = o;
  }
}

// Row LayerNorm over 512 (optional residual add), bf16 out
template<int ADD>
__global__ __launch_bounds__(256) void ln_row(
    const u16* __restrict__ X, const u16* __restrict__ Y,
    const float* __restrict__ w, const float* __restrict__ b,
    u16* __restrict__ outB)
{
  const long row = blockIdx.x;
  const int t = threadIdx.x, lane = t&63, wv = t>>6;
  ushort2 xv = *(const ushort2*)(X + row*512 + t*2);
  float v0 = bf2f(xv.x), v1 = bf2f(xv.y);
  if (ADD){
    ushort2 yv = *(const ushort2*)(Y + row*512 + t*2);
    v0 += bf2f(yv.x); v1 += bf2f(yv.y);
  }
  float s = v0+v1, q = v0*v0 + v1*v1;
  #pragma unroll
  for (int off=32; off; off>>=1){ s += __shfl_xor(s,off); q += __shfl_xor(q,off); }
  __shared__ float red[8];
  if (lane==0){ red[wv]=s; red[4+wv]=q; }
  __syncthreads();
  s = red[0]+red[1]+red[2]+red[3];
  q = red[4]+red[5]+red[6]+red[7];
  const float u = s*(1.0f/512.0f);
  const float var = q*(1.0f/512.0f) - u*u;
  const float inv = rsqrtf(var + 1e-12f);
  const int c = t*2;
  float o0 = (v0-u)*inv*w[c]   + b[c];
  float o1 = (v1-u)*inv*w[c+1] + b[c+1];
  ushort2 ov; ov.x=f2bf(o0); ov.y=f2bf(o1);
  *(ushort2*)(outB + row*512 + c) = ov;
}

// ---------------------------------------------------------------------------
extern "C" void kernel_launch(void* const* d_in, const int* in_sizes, int n_in,
                              void* d_out, int out_size, void* d_ws, size_t ws_size,
                              hipStream_t stream) {
  const float* T1   = (const float*)d_in[0];
  const float* T2   = (const float*)d_in[1];
  const float* w3   = (const float*)d_in[2];
  const float* w1   = (const float*)d_in[3];
  const float* bg   = (const float*)d_in[4];
  const float* bb   = (const float*)d_in[5];
  const float* bm   = (const float*)d_in[6];
  const float* bv   = (const float*)d_in[7];
  const float* ln1w = (const float*)d_in[8];
  const float* ln1b = (const float*)d_in[9];
  const float* linw = (const float*)d_in[10];
  const float* linb = (const float*)d_in[11];
  const float* ln2w = (const float*)d_in[12];
  const float* ln2b = (const float*)d_in[13];

  hipFuncSetAttribute(reinterpret_cast<const void*>(gemm256<0,1>),
                      hipFuncAttributeMaxDynamicSharedMemorySize, 131072);
  hipFuncSetAttribute(reinterpret_cast<const void*>(s_gemm128),
                      hipFuncAttributeMaxDynamicSharedMemorySize, 65536);
  hipFuncSetAttribute(reinterpret_cast<const void*>(pv5),
                      hipFuncAttributeMaxDynamicSharedMemorySize, 65536);
  hipFuncSetAttribute(reinterpret_cast<const void*>(gemm128_deep<0>),
                      hipFuncAttributeMaxDynamicSharedMemorySize, 65536);
  hipFuncSetAttribute(reinterpret_cast<const void*>(gemm128_deep<1>),
                      hipFuncAttributeMaxDynamicSharedMemorySize, 65536);

  char* ws = (char*)d_ws;
  size_t off = 0;
  auto alloc = [&](size_t bytes)->char* {
    char* p = ws + off;
    off += (bytes + 255) & ~(size_t)255;
    return p;
  };
  const size_t XPAD_B = 4L*66*66*1024*2;
  u16*   Xpad  = (u16*)  alloc(XPAD_B);               // aliased as S3 after conv3
  u16*   wk3t  = (u16*)  alloc(1024L*9216*2);
  u16*   w1t   = (u16*)  alloc(512L*1024*2);
  u16*   lint  = (u16*)  alloc(512L*512*2);
  float* bias1 = (float*)alloc(512*4);
  float* nrm   = (float*)alloc(16384L*4);
  u16*   Y1    = (u16*)  alloc(16384L*1024*2);        // aliased as S0 after conv1
  u16*   x0    = (u16*)  alloc(16384L*512*2);         // reused as final bf16 buf
  u16*   xT    = (u16*)  alloc(4L*512*4096*2);
  u16*   Sreg  = (u16*)  alloc(2L*4096*4096*2);       // S1 (lower) + S2 (upper)
  u16*   attb  = (u16*)  alloc(16384L*512*2);
  u16*   h     = (u16*)  alloc(16384L*512*2);
  u16*   g     = (u16*)  alloc(16384L*512*2);
  u16*   rel1  = (u16*)  alloc(16384L*512*2);
  u16*   S0    = Y1;
  u16*   S1    = Sreg;
  u16*   S2    = Sreg + 4096L*4096;
  u16*   S3    = Xpad;
  if (off > ws_size) return;  // workspace too small -> visible failure

  const long ZS = 4096L*512;

  // --- prep ---
  border_zero<<<dim3(260,4), 256, 0, stream>>>(Xpad);
  pad_interior<<<dim3(64,16,4), 256, 0, stream>>>(T1, T2, Xpad);
  prep_w3<<<1024, 256, 0, stream>>>(w3, wk3t);
  prep_small<<<3074, 256, 0, stream>>>(w1, bg, bb, bm, bv, linw, w1t, lint, bias1);

  // --- conv3x3 -> Y1 ; conv1x1+BN+ReLU -> x0 ---
  gemm256<0,1><<<dim3(4,64), 512, 131072, stream>>>(Xpad, wk3t, (void*)Y1, 9216, 0, 9216, 1024);
  gemm128_deep<1><<<512, 256, 65536, stream>>>(Y1, w1t, x0, bias1, 1024, 1024, 1024, 512);

  // --- attention: symmetric batched S-GEMM (128^2 tiles, 2 blk/CU),
  //     batched in-place softmax, pv5 ---
  auto attend = [&](const u16* xin){
    transpose_bf<<<dim3(64,8,4), 256, 0, stream>>>(xin, xT, 4096, 512, ZS, ZS);
    row_norm<<<4096, 256, 0, stream>>>(xin, nrm);
    s_gemm128<<<2112, 256, 65536, stream>>>(xin, nrm, S0, S1, S2, S3);
    softmax_batched<<<16384, 256, 0, stream>>>(S0, S1, S2, S3);
    pv5<<<512, 256, 65536, stream>>>(S0, S1, S2, S3, xT, attb);
  };

  // --- block 1 ---
  attend(x0);
  ln_row<1><<<16384, 256, 0, stream>>>(x0, attb, ln1w, ln1b, h);
  gemm128_deep<1><<<512, 256, 65536, stream>>>(h, lint, g, linb, 512, 512, 512, 512);
  ln_row<0><<<16384, 256, 0, stream>>>(g, nullptr, ln2w, ln2b, rel1);

  // --- block 2 (same params) ---
  attend(rel1);
  ln_row<1><<<16384, 256, 0, stream>>>(rel1, attb, ln1w, ln1b, h);
  gemm128_deep<1><<<512, 256, 65536, stream>>>(h, lint, g, linb, 512, 512, 512, 512);
  ln_row<0><<<16384, 256, 0, stream>>>(g, nullptr, ln2w, ln2b, x0);

  // --- final NHWC bf16 -> NCHW f32 ---
  transpose_bf_f32<<<dim3(64,8,4), 256, 0, stream>>>(x0, (float*)d_out);
}